// Round 3
// baseline (732.591 us; speedup 1.0000x reference)
//
#include <hip/hip_runtime.h>
#include <hip/hip_bf16.h>

#define NUM_OPS   100000
#define NUM_MACH  512
#define HDIM      128
#define P1        100352            // m2o key offset (98*1024)
#define NHIST     200704            // 196*1024 == 784*256 combined key space
#define NBLK      196               // hist scan blocks (1024 elems each)
#define NCOARSE   784               // coarse buckets (key >> 8)
#define NBC       256               // blocks for coarse hist/fill passes
#define NBM       256               // counting-sort blocks for machine buckets
#define MHWORDS   (NUM_MACH * NBM)  // 131072 = 128*1024
#define NBLK_M    128               // blockhist scan blocks

typedef short short8 __attribute__((ext_vector_type(8)));
typedef float floatx4 __attribute__((ext_vector_type(4)));

__device__ __forceinline__ unsigned short f2bf(float f) {
    unsigned u = __float_as_uint(f);
    unsigned r = (u + 0x7FFFu + ((u >> 16) & 1u)) >> 16;   // RNE
    return (unsigned short)r;
}
__device__ __forceinline__ float bf2f(unsigned short u) {
    return __uint_as_float(((unsigned)u) << 16);
}

// ---------------- embedding: out[r,h] = sum_f F[r,f]*W[h,f] + b[h] (+ bf16 mirror) ----------------
__global__ void k_embed(const float* __restrict__ F,
                        const float* __restrict__ W,
                        const float* __restrict__ b,
                        float* __restrict__ out,
                        unsigned short* __restrict__ outb, int M, int FD) {
    int idx = blockIdx.x * blockDim.x + threadIdx.x;
    if (idx >= M * HDIM) return;
    int r = idx >> 7, h = idx & 127;
    const float* f = F + (size_t)r * FD;
    const float* w = W + (size_t)h * FD;
    float s = b[h];
    for (int i = 0; i < FD; ++i) s += f[i] * w[i];
    out[idx] = s;
    if (outb) outb[idx] = f2bf(s);
}

// ---------------- weight convert: Wb[l][h][0:256] = bf16(Wp[l][h] || Wc[l][h]) ----------------
__global__ void k_wconv(const float* __restrict__ Wp, const float* __restrict__ Wc,
                        unsigned short* __restrict__ Wb) {
    int i = blockIdx.x * blockDim.x + threadIdx.x;
    if (i >= 2 * 128 * 256) return;
    int l = i >> 15, h = (i >> 8) & 127, k = i & 255;
    float v = (k < 128) ? Wp[(size_t)l * 16384 + h * 128 + k]
                        : Wc[(size_t)l * 16384 + h * 128 + (k - 128)];
    Wb[i] = f2bf(v);
}

// ---------------- coarse pass A: per-block LDS histograms over key>>8 ----------------
__global__ __launch_bounds__(256) void k_chist(const int* __restrict__ prec_e, int nprec,
                                               const int* __restrict__ comp_e, int E,
                                               int* __restrict__ blockhist) {
    __shared__ int h[NCOARSE];
    for (int i = threadIdx.x; i < NCOARSE; i += 256) h[i] = 0;
    __syncthreads();
    int NT = nprec + E;
    int ch = (NT + NBC - 1) / NBC;
    int i0 = blockIdx.x * ch, i1 = min(NT, i0 + ch);
    for (int i = i0 + threadIdx.x; i < i1; i += 256) {
        int key = (i < nprec) ? prec_e[nprec + i] : (P1 + comp_e[i - nprec]);
        atomicAdd(&h[key >> 8], 1);
    }
    __syncthreads();
    for (int i = threadIdx.x; i < NCOARSE; i += 256)
        blockhist[i * NBC + blockIdx.x] = h[i];
}

// ---------------- coarse pass B: place packed (val<<8 | key&255) via LDS cursors ----------------
__global__ __launch_bounds__(256) void k_cfill(const int* __restrict__ prec_e, int nprec,
                                               const int* __restrict__ comp_e, int E, int M,
                                               const int* __restrict__ scan,
                                               int* __restrict__ pairs) {
    __shared__ int cur[NCOARSE];
    for (int i = threadIdx.x; i < NCOARSE; i += 256) cur[i] = scan[i * NBC + blockIdx.x];
    __syncthreads();
    int NT = nprec + E;
    int ch = (NT + NBC - 1) / NBC;
    int i0 = blockIdx.x * ch, i1 = min(NT, i0 + ch);
    for (int i = i0 + threadIdx.x; i < i1; i += 256) {
        int key, val;
        if (i < nprec) { key = prec_e[nprec + i]; val = prec_e[i]; }
        else { int e = i - nprec; key = P1 + comp_e[e]; val = comp_e[E + e] - M; }
        int pos = atomicAdd(&cur[key >> 8], 1);
        pairs[pos] = (val << 8) | (key & 255);
    }
}

// ---------------- fine pass: per-coarse-bucket counting sort (256 keys, LDS) ----------------
__global__ __launch_bounds__(256) void k_fine(const int* __restrict__ scan,
                                              const int* __restrict__ pairs, int NT,
                                              int* __restrict__ rs,
                                              int* __restrict__ bucket_all) {
    __shared__ int hh[256];
    __shared__ int ex[256];
    __shared__ int cu[256];
    int b = blockIdx.x, t = threadIdx.x;
    int s = scan[b * NBC];
    int e = (b == NCOARSE - 1) ? NT : scan[(b + 1) * NBC];
    hh[t] = 0;
    __syncthreads();
    for (int i = s + t; i < e; i += 256) atomicAdd(&hh[pairs[i] & 255], 1);
    __syncthreads();
    int v = hh[t];
    ex[t] = v; __syncthreads();
    for (int o = 1; o < 256; o <<= 1) {
        int x = (t >= o) ? ex[t - o] : 0; __syncthreads();
        ex[t] += x; __syncthreads();
    }
    int start = s + ex[t] - v;      // exclusive offset for key b*256+t
    rs[b * 256 + t] = start;
    cu[t] = start;
    __syncthreads();
    for (int i = s + t; i < e; i += 256) {
        int p = pairs[i];
        int pos = atomicAdd(&cu[p & 255], 1);
        bucket_all[pos] = ((unsigned)p) >> 8;
    }
}

// ---------------- machine counting-sort pass A: per-block LDS histograms ----------------
__global__ __launch_bounds__(256) void k_mhist(const int* __restrict__ comp_e, int E, int M,
                                               int* __restrict__ blockhist) {
    __shared__ int h[NUM_MACH];
    for (int i = threadIdx.x; i < NUM_MACH; i += 256) h[i] = 0;
    __syncthreads();
    int blk = blockIdx.x;
    int ch = (E + NBM - 1) / NBM;
    int e0 = blk * ch, e1 = min(E, e0 + ch);
    for (int e = e0 + threadIdx.x; e < e1; e += 256)
        atomicAdd(&h[comp_e[E + e] - M], 1);
    __syncthreads();
    for (int i = threadIdx.x; i < NUM_MACH; i += 256)
        blockhist[i * NBM + blk] = h[i];
}

// ---------------- scan phase 1: per-block sums (1024 ints / block) ----------------
__global__ __launch_bounds__(256) void k_blocksum(const int* __restrict__ arr, int* __restrict__ partial) {
    __shared__ int sh[256];
    int b = blockIdx.x, t = threadIdx.x;
    int4 v = *(const int4*)(arr + b * 1024 + t * 4);
    sh[t] = v.x + v.y + v.z + v.w;
    __syncthreads();
    for (int o = 128; o; o >>= 1) { if (t < o) sh[t] += sh[t + o]; __syncthreads(); }
    if (!t) partial[b] = sh[0];
}

// ---------------- scan phase 2: exclusive scan of <=256 partials, single block ----------------
__global__ __launch_bounds__(256) void k_scanpart(const int* __restrict__ partial, int n,
                                                  int* __restrict__ block_off) {
    __shared__ int sh[256];
    int t = threadIdx.x;
    int v = (t < n) ? partial[t] : 0;
    sh[t] = v; __syncthreads();
    for (int o = 1; o < 256; o <<= 1) {
        int x = (t >= o) ? sh[t - o] : 0; __syncthreads();
        sh[t] += x; __syncthreads();
    }
    if (t < n) block_off[t] = sh[t] - v;
}

// ---------------- scan phase 3: write exclusive offsets ----------------
__global__ __launch_bounds__(256) void k_scanwrite(const int* __restrict__ arr,
                                                   const int* __restrict__ block_off,
                                                   int* __restrict__ rs, int* __restrict__ cur) {
    __shared__ int sh[256];
    int b = blockIdx.x, t = threadIdx.x;
    int base_i = b * 1024 + t * 4;
    int4 v = *(const int4*)(arr + base_i);
    int tsum = v.x + v.y + v.z + v.w;
    sh[t] = tsum; __syncthreads();
    for (int o = 1; o < 256; o <<= 1) {
        int x = (t >= o) ? sh[t - o] : 0; __syncthreads();
        sh[t] += x; __syncthreads();
    }
    int off = block_off[b] + sh[t] - tsum;
    int4 r; r.x = off; r.y = off + v.x; r.z = off + v.x + v.y; r.w = off + v.x + v.y + v.z;
    *(int4*)(rs + base_i) = r;
    if (cur) *(int4*)(cur + base_i) = r;
}

// ---------------- extract machine row starts from scanned blockhist column 0 ----------------
__global__ void k_machrs(const int* __restrict__ moff, int* __restrict__ mach_rs, int E) {
    int t = threadIdx.x;
    for (int m = t; m < NUM_MACH; m += 256) mach_rs[m] = moff[m * NBM];
    if (t == 0) mach_rs[NUM_MACH] = E;
}

// ---------------- machine counting-sort pass B: placement via LDS cursors ----------------
__global__ __launch_bounds__(256) void k_fill_mach(const int* __restrict__ comp_e, int E, int M,
                                                   const int* __restrict__ moff,
                                                   int* __restrict__ bucket_mach) {
    __shared__ int cur[NUM_MACH];
    int blk = blockIdx.x;
    for (int i = threadIdx.x; i < NUM_MACH; i += 256) cur[i] = moff[i * NBM + blk];
    __syncthreads();
    int ch = (E + NBM - 1) / NBM;
    int e0 = blk * ch, e1 = min(E, e0 + ch);
    for (int e = e0 + threadIdx.x; e < e1; e += 256) {
        int m = comp_e[E + e] - M;
        int op = comp_e[e];
        int pos = atomicAdd(&cur[m], 1);
        bucket_mach[pos] = op;
    }
}

// ---------------- FUSED: gather means -> LDS (swizzled) -> MFMA -> residual+LN ----------------
// Each wave owns 16 rows: gathers prec (bf16 op_ebf) + m2o (f32 mach_emb) means into its own
// LDS sub-tile, then runs the 16x16x32 MFMA tile. No cross-wave LDS deps -> no barrier.
// LDS swizzle: 16B-chunk index ^= (row&7) -> 2-way bank conflict (free) on ds_read_b128.
__global__ __launch_bounds__(256) void k_fused(
    const unsigned short* __restrict__ op_ebf, const float* __restrict__ mach_emb,
    const int* __restrict__ rs, const int* __restrict__ bucket_all,
    const float* __restrict__ emb,
    const unsigned short* __restrict__ Wb,
    const float* __restrict__ bp, const float* __restrict__ bc,
    const float* __restrict__ g, const float* __restrict__ bt,
    float* __restrict__ dst, unsigned short* __restrict__ dstb, int M) {
    __shared__ unsigned short At[64 * 256];   // 32 KB, rows 512 B, chunk-swizzled
    int wave = threadIdx.x >> 6, lane = threadIdx.x & 63;
    int m0 = blockIdx.x * 64 + wave * 16;
    if (m0 >= M) return;
    int h = lane * 2;
    unsigned fl_packed = 0;

    for (int i = 0; i < 16; ++i) {
        int r = m0 + i;
        int ri = wave * 16 + i;

        float a0 = 0.f, a1 = 0.f;
        int s0 = rs[r], e0 = rs[r + 1];
        for (int base = s0; base < e0; base += 64) {
            int cnt = min(64, e0 - base);
            int idx = (lane < cnt) ? bucket_all[base + lane] : 0;
            for (int j = 0; j < cnt; j += 4) {
                int i0 = __shfl(idx, j);
                int i1 = __shfl(idx, j + 1);
                int i2 = __shfl(idx, j + 2);
                int i3 = __shfl(idx, j + 3);
                ushort2 v0 = *(const ushort2*)(op_ebf + (size_t)i0 * HDIM + h);
                ushort2 v1 = *(const ushort2*)(op_ebf + (size_t)i1 * HDIM + h);
                ushort2 v2 = *(const ushort2*)(op_ebf + (size_t)i2 * HDIM + h);
                ushort2 v3 = *(const ushort2*)(op_ebf + (size_t)i3 * HDIM + h);
                a0 += bf2f(v0.x); a1 += bf2f(v0.y);
                if (j + 1 < cnt) { a0 += bf2f(v1.x); a1 += bf2f(v1.y); }
                if (j + 2 < cnt) { a0 += bf2f(v2.x); a1 += bf2f(v2.y); }
                if (j + 3 < cnt) { a0 += bf2f(v3.x); a1 += bf2f(v3.y); }
            }
        }
        float pinv = 1.f / fmaxf((float)(e0 - s0), 1.f);

        float b0 = 0.f, b1 = 0.f;
        int s1 = rs[P1 + r], e1 = rs[P1 + r + 1];
        for (int base = s1; base < e1; base += 64) {
            int cnt = min(64, e1 - base);
            int idx = (lane < cnt) ? bucket_all[base + lane] : 0;
            for (int j = 0; j < cnt; j += 4) {
                int i0 = __shfl(idx, j);
                int i1 = __shfl(idx, j + 1);
                int i2 = __shfl(idx, j + 2);
                int i3 = __shfl(idx, j + 3);
                float2 v0 = *(const float2*)(mach_emb + (size_t)i0 * HDIM + h);
                float2 v1 = *(const float2*)(mach_emb + (size_t)i1 * HDIM + h);
                float2 v2 = *(const float2*)(mach_emb + (size_t)i2 * HDIM + h);
                float2 v3 = *(const float2*)(mach_emb + (size_t)i3 * HDIM + h);
                b0 += v0.x; b1 += v0.y;
                if (j + 1 < cnt) { b0 += v1.x; b1 += v1.y; }
                if (j + 2 < cnt) { b0 += v2.x; b1 += v2.y; }
                if (j + 3 < cnt) { b0 += v3.x; b1 += v3.y; }
            }
        }
        float cinv = 1.f / fmaxf((float)(e1 - s1), 1.f);

        ushort2 pa, pb;
        pa.x = f2bf(a0 * pinv); pa.y = f2bf(a1 * pinv);
        pb.x = f2bf(b0 * cinv); pb.y = f2bf(b1 * cinv);
        unsigned sw = (ri & 7) << 4;
        *(ushort2*)((char*)At + ri * 512 + ((lane * 4) ^ sw))       = pa;
        *(ushort2*)((char*)At + ri * 512 + ((256 + lane * 4) ^ sw)) = pb;
        fl_packed |= ((e0 > s0 ? 1u : 0u) | (e1 > s1 ? 2u : 0u)) << (2 * i);
    }

    // ---- MFMA phase (reads only this wave's LDS rows; in-wave lgkmcnt ordering suffices) ----
    int quad = lane >> 4, col = lane & 15;
    int ri = wave * 16 + col;
    unsigned swr = (ri & 7) << 4;

    floatx4 acc[8];
#pragma unroll
    for (int t = 0; t < 8; ++t) acc[t] = (floatx4){0.f, 0.f, 0.f, 0.f};

    const short* Wbase = (const short*)Wb;
#pragma unroll
    for (int ks = 0; ks < 8; ++ks) {
        short8 a = *(const short8*)((const char*)At + ri * 512 + ((ks * 64 + quad * 16) ^ swr));
#pragma unroll
        for (int t = 0; t < 8; ++t) {
            short8 b = *(const short8*)(Wbase + (size_t)(t * 16 + col) * 256 + ks * 32 + quad * 8);
            acc[t] = __builtin_amdgcn_mfma_f32_16x16x32_bf16(a, b, acc[t], 0, 0, 0);
        }
    }

    float bpv[8], bcv[8], gv[8], btv[8];
#pragma unroll
    for (int t = 0; t < 8; ++t) {
        int c = t * 16 + col;
        bpv[t] = bp[c]; bcv[t] = bc[c]; gv[t] = g[c]; btv[t] = bt[c];
    }
#pragma unroll
    for (int reg = 0; reg < 4; ++reg) {
        int r = m0 + quad * 4 + reg;
        int fl = (fl_packed >> ((quad * 4 + reg) * 2)) & 3;
        float fp = (fl & 1) ? 1.f : 0.f, fc = (fl & 2) ? 1.f : 0.f;
        float x[8]; float s = 0.f, q = 0.f;
#pragma unroll
        for (int t = 0; t < 8; ++t) {
            float v = acc[t][reg] + emb[(size_t)r * HDIM + t * 16 + col] + fp * bpv[t] + fc * bcv[t];
            x[t] = v; s += v; q += v * v;
        }
#pragma unroll
        for (int msk = 1; msk < 16; msk <<= 1) { s += __shfl_xor(s, msk); q += __shfl_xor(q, msk); }
        float mu = s * (1.f / 128.f);
        float rstd = rsqrtf(fmaxf(q * (1.f / 128.f) - mu * mu, 0.f) + 1e-5f);
#pragma unroll
        for (int t = 0; t < 8; ++t) {
            float y = (x[t] - mu) * rstd * gv[t] + btv[t];
            dst[(size_t)r * HDIM + t * 16 + col] = y;
            if (dstb) dstb[(size_t)r * HDIM + t * 16 + col] = f2bf(y);
        }
    }
}

// ---------------- machine gather (bf16 rows): wave owns 64-edge batch, full row ----------------
__global__ __launch_bounds__(256) void k_mach_gather(
    const int* __restrict__ mach_rs, const int* __restrict__ bucket_mach,
    const unsigned short* __restrict__ op_ebf, float* __restrict__ mach_sum) {
    int m = blockIdx.x;
    int t = threadIdx.x;
    int wave = t >> 6, lane = t & 63;
    int h = lane * 2;
    int s0 = mach_rs[m], e0 = mach_rs[m + 1];
    float a0 = 0.f, a1 = 0.f;
    for (int base = s0 + (blockIdx.y * 4 + wave) * 64; base < e0; base += gridDim.y * 256) {
        int cnt = min(64, e0 - base);
        int idx = (lane < cnt) ? bucket_mach[base + lane] : 0;
        for (int j = 0; j < cnt; j += 4) {
            int i0 = __shfl(idx, j);
            int i1 = __shfl(idx, j + 1);
            int i2 = __shfl(idx, j + 2);
            int i3 = __shfl(idx, j + 3);
            ushort2 v0 = *(const ushort2*)(op_ebf + (size_t)i0 * HDIM + h);
            ushort2 v1 = *(const ushort2*)(op_ebf + (size_t)i1 * HDIM + h);
            ushort2 v2 = *(const ushort2*)(op_ebf + (size_t)i2 * HDIM + h);
            ushort2 v3 = *(const ushort2*)(op_ebf + (size_t)i3 * HDIM + h);
            a0 += bf2f(v0.x); a1 += bf2f(v0.y);
            if (j + 1 < cnt) { a0 += bf2f(v1.x); a1 += bf2f(v1.y); }
            if (j + 2 < cnt) { a0 += bf2f(v2.x); a1 += bf2f(v2.y); }
            if (j + 3 < cnt) { a0 += bf2f(v3.x); a1 += bf2f(v3.y); }
        }
    }
    atomicAdd(&mach_sum[m * HDIM + h], a0);
    atomicAdd(&mach_sum[m * HDIM + h + 1], a1);
}

// ---------------- machine update: mean -> @Wc^T + bc -> +emb -> LN ----------------
__global__ __launch_bounds__(128) void k_mach_update(
    const float* __restrict__ mach_emb, const float* __restrict__ mach_sum,
    const int* __restrict__ mach_rs,
    const float* __restrict__ Wc, const float* __restrict__ bc,
    const float* __restrict__ g, const float* __restrict__ bt,
    float* __restrict__ dst) {
    __shared__ float row[HDIM];
    __shared__ float red[4];
    int m = blockIdx.x, t = threadIdx.x;
    int cnt = mach_rs[m + 1] - mach_rs[m];
    float sc = (cnt > 0) ? 1.f / (float)cnt : 0.f;
    row[t] = mach_sum[m * HDIM + t] * sc;
    __syncthreads();
    float dot = bc[t];
    const float* w = Wc + (size_t)t * HDIM;
#pragma unroll 8
    for (int k = 0; k < HDIM; ++k) dot += row[k] * w[k];
    float x = mach_emb[m * HDIM + t] + ((cnt > 0) ? dot : 0.f);
    float s = x, q = x * x;
#pragma unroll
    for (int o = 32; o; o >>= 1) { s += __shfl_xor(s, o); q += __shfl_xor(q, o); }
    int wv = t >> 6;
    if ((t & 63) == 0) { red[wv * 2] = s; red[wv * 2 + 1] = q; }
    __syncthreads();
    s = red[0] + red[2]; q = red[1] + red[3];
    float mu = s * (1.f / 128.f);
    float rstd = rsqrtf(fmaxf(q * (1.f / 128.f) - mu * mu, 0.f) + 1e-5f);
    dst[m * HDIM + t] = (x - mu) * rstd * g[t] + bt[t];
}

extern "C" void kernel_launch(void* const* d_in, const int* in_sizes, int n_in,
                              void* d_out, int out_size, void* d_ws, size_t ws_size,
                              hipStream_t stream) {
    const float* op_feat    = (const float*)d_in[0];
    const float* m_feat     = (const float*)d_in[1];
    const int*   prec_e     = (const int*)d_in[2];
    const int*   comp_e     = (const int*)d_in[3];
    const float* op_emb_W   = (const float*)d_in[4];
    const float* op_emb_b   = (const float*)d_in[5];
    const float* mach_emb_W = (const float*)d_in[6];
    const float* mach_emb_b = (const float*)d_in[7];
    const float* prec_W     = (const float*)d_in[8];
    const float* prec_b     = (const float*)d_in[9];
    const float* compat_W   = (const float*)d_in[10];
    const float* compat_b   = (const float*)d_in[11];
    const float* op_ln_g    = (const float*)d_in[12];
    const float* op_ln_b    = (const float*)d_in[13];
    const float* mach_ln_g  = (const float*)d_in[14];
    const float* mach_ln_b  = (const float*)d_in[15];
    float* out = (float*)d_out;

    const int M = NUM_OPS, NM = NUM_MACH;
    const int nprec = in_sizes[2] / 2;
    const int ncomp = in_sizes[3] / 2;
    const int E = ncomp / 2;   // bidirectional pairs: first half o2m, second half m2o (mirror)
    const int NT = nprec + E;

    float* ws = (float*)d_ws;
    size_t o = 0;
    float* op_emb   = ws + o; o += (size_t)M * HDIM;    // 51 MB (in-place residual+dst)
    unsigned short* op_ebfA = (unsigned short*)(ws + o); o += (size_t)M * 64;  // 25.6 MB bf16 mirror A
    unsigned short* op_ebfB = (unsigned short*)(ws + o); o += (size_t)M * 64;  // 25.6 MB bf16 mirror B
    unsigned short* Wb = (unsigned short*)(ws + o); o += 32768;            // 2 layers x [128][256] bf16
    float* mach_emb = ws + o; o += (size_t)NM * HDIM;
    float* mach_sum = ws + o; o += (size_t)NM * HDIM;
    int* ip = (int*)(ws + o);
    size_t io = 0;
    int* chist     = ip + io; io += NHIST;     // coarse blockhist [784][256]
    int* rs        = ip + io; io += NHIST;     // fine row starts (exclusive)
    int* cscan     = ip + io; io += NHIST;     // scanned coarse blockhist
    int* blockhist = ip + io; io += MHWORDS;
    int* moff      = ip + io; io += MHWORDS;
    int* mach_rs   = ip + io; io += NM + 8;
    int* partialA  = ip + io; io += 256;
    int* block_offA= ip + io; io += 256;
    int* partialB  = ip + io; io += 256;
    int* block_offB= ip + io; io += 256;
    int* pairs     = ip + io; io += (size_t)NT;               // coarse-partitioned packed edges
    int* bucket_all  = ip + io; io += (size_t)NT;
    int* bucket_mach = ip + io; io += (size_t)E;

    // ---- CSR build: two-level counting sort (no global scattered atomics) ----
    k_chist<<<NBC, 256, 0, stream>>>(prec_e, nprec, comp_e, E, chist);
    k_mhist<<<NBM, 256, 0, stream>>>(comp_e, E, M, blockhist);
    k_blocksum<<<NBLK, 256, 0, stream>>>(chist, partialA);
    k_scanpart<<<1, 256, 0, stream>>>(partialA, NBLK, block_offA);
    k_scanwrite<<<NBLK, 256, 0, stream>>>(chist, block_offA, cscan, nullptr);
    k_blocksum<<<NBLK_M, 256, 0, stream>>>(blockhist, partialB);
    k_scanpart<<<1, 256, 0, stream>>>(partialB, NBLK_M, block_offB);
    k_scanwrite<<<NBLK_M, 256, 0, stream>>>(blockhist, block_offB, moff, nullptr);
    k_machrs<<<1, 256, 0, stream>>>(moff, mach_rs, E);
    k_cfill<<<NBC, 256, 0, stream>>>(prec_e, nprec, comp_e, E, M, cscan, pairs);
    k_fine<<<NCOARSE, 256, 0, stream>>>(cscan, pairs, NT, rs, bucket_all);
    k_fill_mach<<<NBM, 256, 0, stream>>>(comp_e, E, M, moff, bucket_mach);

    // ---- input embeddings + weight conversion ----
    k_embed<<<(M * HDIM + 255) / 256, 256, 0, stream>>>(op_feat, op_emb_W, op_emb_b, op_emb, op_ebfA, M, 6);
    k_embed<<<(NM * HDIM + 255) / 256, 256, 0, stream>>>(m_feat, mach_emb_W, mach_emb_b, mach_emb, nullptr, NM, 2);
    k_wconv<<<(2 * 128 * 256 + 255) / 256, 256, 0, stream>>>(prec_W, compat_W, Wb);

    for (int l = 0; l < 2; ++l) {
        int last = (l == 1);
        const unsigned short* ebf_src = (l == 0) ? op_ebfA : op_ebfB;
        unsigned short* ebf_dst = (l == 0) ? op_ebfB : nullptr;
        const float* bpl = prec_b   + (size_t)l * HDIM;
        const float* Wc  = compat_W + (size_t)l * HDIM * HDIM;
        const float* bcl = compat_b + (size_t)l * HDIM;

        hipMemsetAsync(mach_sum, 0, (size_t)NM * HDIM * sizeof(float), stream);

        // fused agg+GEMM reads ebf_src (old bf16 mirror) + mach_emb (old); writes op_emb
        // in-place (own rows only) + new mirror ebf_dst
        k_fused<<<(M + 63) / 64, 256, 0, stream>>>(
            ebf_src, mach_emb, rs, bucket_all, op_emb,
            Wb + (size_t)l * 128 * 256, bpl, bcl,
            op_ln_g + (size_t)l * HDIM, op_ln_b + (size_t)l * HDIM,
            last ? out : op_emb, ebf_dst, M);

        // machine-side gather reads OLD mirror (ebf_src), unaffected by k_fused's writes
        k_mach_gather<<<dim3(NM, 4), 256, 0, stream>>>(mach_rs, bucket_mach, ebf_src, mach_sum);

        // machine update (runs after all reads of old mach_emb)
        k_mach_update<<<NM, 128, 0, stream>>>(
            mach_emb, mach_sum, mach_rs, Wc, bcl,
            mach_ln_g + (size_t)l * HDIM, mach_ln_b + (size_t)l * HDIM,
            last ? (out + (size_t)M * HDIM) : mach_emb);
    }
}

// Round 6
// 579.094 us; speedup vs baseline: 1.2651x; 1.2651x over previous
//
#include <hip/hip_runtime.h>
#include <hip/hip_bf16.h>

#define NUM_OPS   100000
#define NUM_MACH  512
#define HDIM      128
#define P1        100352            // m2o key offset (98*1024)
#define NHIST     200704            // 196*1024 == 784*256 combined key space
#define NBLK      196               // op-hist scan blocks (1024 elems each)
#define NCOARSE   784               // coarse buckets (key >> 8)
#define NBC       256               // blocks for coarse hist/fill passes
#define NBM       256               // counting-sort blocks for machine buckets
#define MHWORDS   (NUM_MACH * NBM)  // 131072 = 128*1024
#define NBLK_M    128               // machine blockhist scan blocks
#define NBLK_T    (NBLK + NBLK_M)   // 324 unified scan blocks

typedef short short8 __attribute__((ext_vector_type(8)));
typedef float floatx4 __attribute__((ext_vector_type(4)));

__device__ __forceinline__ unsigned short f2bf(float f) {
    unsigned u = __float_as_uint(f);
    unsigned r = (u + 0x7FFFu + ((u >> 16) & 1u)) >> 16;   // RNE
    return (unsigned short)r;
}
__device__ __forceinline__ float bf2f(unsigned short u) {
    return __uint_as_float(((unsigned)u) << 16);
}

// ---------------- prep: op embed (+mirror) | mach embed | weight convert, one launch ----------
__global__ void k_prep(const float* __restrict__ Fo, const float* __restrict__ Fm,
                       const float* __restrict__ Wo, const float* __restrict__ bo,
                       const float* __restrict__ Wm, const float* __restrict__ bm,
                       const float* __restrict__ Wp, const float* __restrict__ Wc,
                       float* __restrict__ op_emb, unsigned short* __restrict__ op_ebf,
                       float* __restrict__ mach_emb, unsigned short* __restrict__ Wb) {
    int idx = blockIdx.x * blockDim.x + threadIdx.x;
    if (idx < NUM_OPS * HDIM) {
        int r = idx >> 7, h = idx & 127;
        const float* f = Fo + (size_t)r * 6;
        const float* w = Wo + (size_t)h * 6;
        float s = bo[h];
#pragma unroll
        for (int i = 0; i < 6; ++i) s += f[i] * w[i];
        op_emb[idx] = s;
        op_ebf[idx] = f2bf(s);
        return;
    }
    idx -= NUM_OPS * HDIM;
    if (idx < NUM_MACH * HDIM) {
        int r = idx >> 7, h = idx & 127;
        const float* f = Fm + (size_t)r * 2;
        const float* w = Wm + (size_t)h * 2;
        mach_emb[idx] = bm[h] + f[0] * w[0] + f[1] * w[1];
        return;
    }
    idx -= NUM_MACH * HDIM;
    if (idx < 2 * 128 * 256) {
        int l = idx >> 15, h = (idx >> 8) & 127, k = idx & 255;
        float v = (k < 128) ? Wp[(size_t)l * 16384 + h * 128 + k]
                            : Wc[(size_t)l * 16384 + h * 128 + (k - 128)];
        Wb[idx] = f2bf(v);
    }
}

// ---------------- front: coarse op-key histogram + machine histogram (shared comp_e read) ----
// BOTH histograms are chunked over the unified i-space [0, NT): column j counts items in
// i-chunk j. Downstream placement kernels must use the SAME i-chunk ranges (bug fixed r6).
__global__ __launch_bounds__(256) void k_front(const int* __restrict__ prec_e, int nprec,
                                               const int* __restrict__ comp_e, int E, int M,
                                               int* __restrict__ chist_bh,   // [784][256]
                                               int* __restrict__ mach_bh) {  // [512][256]
    __shared__ int hc[NCOARSE];
    __shared__ int hm[NUM_MACH];
    for (int i = threadIdx.x; i < NCOARSE; i += 256) hc[i] = 0;
    for (int i = threadIdx.x; i < NUM_MACH; i += 256) hm[i] = 0;
    __syncthreads();
    int NT = nprec + E;
    int ch = (NT + NBC - 1) / NBC;
    int i0 = blockIdx.x * ch, i1 = min(NT, i0 + ch);
    for (int i = i0 + threadIdx.x; i < i1; i += 256) {
        int key;
        if (i < nprec) key = prec_e[nprec + i];
        else {
            int e = i - nprec;
            key = P1 + comp_e[e];
            atomicAdd(&hm[comp_e[E + e] - M], 1);
        }
        atomicAdd(&hc[key >> 8], 1);
    }
    __syncthreads();
    for (int i = threadIdx.x; i < NCOARSE; i += 256)
        chist_bh[i * NBC + blockIdx.x] = hc[i];
    for (int i = threadIdx.x; i < NUM_MACH; i += 256)
        mach_bh[i * NBC + blockIdx.x] = hm[i];
}

// ---------------- coarse pass B: place packed (val<<8 | key&255) via LDS cursors ----------------
__global__ __launch_bounds__(256) void k_cfill(const int* __restrict__ prec_e, int nprec,
                                               const int* __restrict__ comp_e, int E, int M,
                                               const int* __restrict__ scan,
                                               int* __restrict__ pairs) {
    __shared__ int cur[NCOARSE];
    for (int i = threadIdx.x; i < NCOARSE; i += 256) cur[i] = scan[i * NBC + blockIdx.x];
    __syncthreads();
    int NT = nprec + E;
    int ch = (NT + NBC - 1) / NBC;
    int i0 = blockIdx.x * ch, i1 = min(NT, i0 + ch);
    for (int i = i0 + threadIdx.x; i < i1; i += 256) {
        int key, val;
        if (i < nprec) { key = prec_e[nprec + i]; val = prec_e[i]; }
        else { int e = i - nprec; key = P1 + comp_e[e]; val = comp_e[E + e] - M; }
        int pos = atomicAdd(&cur[key >> 8], 1);
        pairs[pos] = (val << 8) | (key & 255);
    }
}

// ---------------- scan phase 1: per-block sums over unified [chist|mach_bh] ----------------
__global__ __launch_bounds__(256) void k_blocksum(const int* __restrict__ arr, int* __restrict__ partial) {
    __shared__ int sh[256];
    int b = blockIdx.x, t = threadIdx.x;
    int4 v = *(const int4*)(arr + b * 1024 + t * 4);
    sh[t] = v.x + v.y + v.z + v.w;
    __syncthreads();
    for (int o = 128; o; o >>= 1) { if (t < o) sh[t] += sh[t + o]; __syncthreads(); }
    if (!t) partial[b] = sh[0];
}

// ---------------- scan phase 2: two independent segments (op: 196, machine: 128) --------------
__global__ __launch_bounds__(256) void k_scanpart(const int* __restrict__ partial,
                                                  int* __restrict__ block_off) {
    __shared__ int sh[256];
    int t = threadIdx.x;
    int seg0 = blockIdx.x ? NBLK : 0;
    int n    = blockIdx.x ? NBLK_M : NBLK;
    int v = (t < n) ? partial[seg0 + t] : 0;
    sh[t] = v; __syncthreads();
    for (int o = 1; o < 256; o <<= 1) {
        int x = (t >= o) ? sh[t - o] : 0; __syncthreads();
        sh[t] += x; __syncthreads();
    }
    if (t < n) block_off[seg0 + t] = sh[t] - v;
}

// ---------------- scan phase 3: write exclusive offsets (unified) ----------------
__global__ __launch_bounds__(256) void k_scanwrite(const int* __restrict__ arr,
                                                   const int* __restrict__ block_off,
                                                   int* __restrict__ rs) {
    __shared__ int sh[256];
    int b = blockIdx.x, t = threadIdx.x;
    int base_i = b * 1024 + t * 4;
    int4 v = *(const int4*)(arr + base_i);
    int tsum = v.x + v.y + v.z + v.w;
    sh[t] = tsum; __syncthreads();
    for (int o = 1; o < 256; o <<= 1) {
        int x = (t >= o) ? sh[t - o] : 0; __syncthreads();
        sh[t] += x; __syncthreads();
    }
    int off = block_off[b] + sh[t] - tsum;
    int4 r; r.x = off; r.y = off + v.x; r.z = off + v.x + v.y; r.w = off + v.x + v.y + v.z;
    *(int4*)(rs + base_i) = r;
}

// ---------------- fine counting sort (op keys) + machine placement + mach_rs, one launch -----
// Machine branch (r6 FIX): process the e-range of NT-chunk blk, matching k_front's columns:
// e in [blk*chNT - nprec, (blk+1)*chNT - nprec) clamped to [0, E). Mismatched chunking
// (E-chunks vs NT-chunk cursors) made cursors overrun bucket_mach -> ws overflow -> fault.
__global__ __launch_bounds__(256) void k_finefill(const int* __restrict__ scans, int NT,
                                                  const int* __restrict__ pairs,
                                                  int* __restrict__ rs,
                                                  int* __restrict__ bucket_all,
                                                  const int* __restrict__ comp_e, int E, int M,
                                                  int* __restrict__ bucket_mach,
                                                  int* __restrict__ mach_rs) {
    int t = threadIdx.x;
    if (blockIdx.x < NCOARSE) {
        // fine pass: per-coarse-bucket counting sort (256 keys, LDS)
        __shared__ int hh[256];
        __shared__ int ex[256];
        __shared__ int cu[256];
        int b = blockIdx.x;
        int s = scans[b * NBC];
        int e = (b == NCOARSE - 1) ? NT : scans[(b + 1) * NBC];
        hh[t] = 0;
        __syncthreads();
        for (int i = s + t; i < e; i += 256) atomicAdd(&hh[pairs[i] & 255], 1);
        __syncthreads();
        int v = hh[t];
        ex[t] = v; __syncthreads();
        for (int o = 1; o < 256; o <<= 1) {
            int x = (t >= o) ? ex[t - o] : 0; __syncthreads();
            ex[t] += x; __syncthreads();
        }
        int start = s + ex[t] - v;
        rs[b * 256 + t] = start;
        cu[t] = start;
        __syncthreads();
        for (int i = s + t; i < e; i += 256) {
            int p = pairs[i];
            int pos = atomicAdd(&cu[p & 255], 1);
            bucket_all[pos] = ((unsigned)p) >> 8;
        }
    } else {
        // machine placement via LDS cursors (+ block 0 copies mach_rs)
        __shared__ int cur[NUM_MACH];
        int blk = blockIdx.x - NCOARSE;
        const int* moff = scans + NHIST;
        for (int i = t; i < NUM_MACH; i += 256) cur[i] = moff[i * NBM + blk];
        if (blk == 0) {
            for (int m = t; m < NUM_MACH; m += 256) mach_rs[m] = moff[m * NBM];
            if (t == 0) mach_rs[NUM_MACH] = E;
        }
        __syncthreads();
        int nprec = NT - E;
        int chNT = (NT + NBC - 1) / NBC;            // SAME chunking as k_front
        int e0 = blk * chNT - nprec;       if (e0 < 0) e0 = 0;
        int e1 = (blk + 1) * chNT - nprec; if (e1 > E) e1 = E;
        for (int e = e0 + t; e < e1; e += 256) {
            int m = comp_e[E + e] - M;
            int op = comp_e[e];
            int pos = atomicAdd(&cur[m], 1);
            bucket_mach[pos] = op;
        }
    }
}

// ---------------- merged per-layer aggregation: op-side gather->Ab | machine-side gather ------
// blocks [0, nb_agg): op aggregation (verbatim r2 k_agg_op)
// blocks [nb_agg, nb_agg+2048): machine gather, short8 rows (16 lanes/row, 4 edges/iter)
__global__ __launch_bounds__(256) void k_aggmg(
    const unsigned short* __restrict__ op_ebf, const float* __restrict__ mach_emb,
    const int* __restrict__ rs, const int* __restrict__ bucket_all,
    unsigned short* __restrict__ Ab, int* __restrict__ flags, int M,
    const int* __restrict__ mach_rs, const int* __restrict__ bucket_mach,
    float* __restrict__ mach_sum, int nb_agg) {
    int wave = threadIdx.x >> 6, lane = threadIdx.x & 63;

    if ((int)blockIdx.x < nb_agg) {
        // ---- op aggregation path ----
        int r = blockIdx.x * 4 + wave;
        if (r >= M) return;
        int h = lane * 2;

        float a0 = 0.f, a1 = 0.f;
        int s0 = rs[r], e0 = rs[r + 1];
        for (int base = s0; base < e0; base += 64) {
            int cnt = min(64, e0 - base);
            int idx = (lane < cnt) ? bucket_all[base + lane] : 0;
            for (int j = 0; j < cnt; j += 4) {
                int i0 = __shfl(idx, j);
                int i1 = __shfl(idx, j + 1);
                int i2 = __shfl(idx, j + 2);
                int i3 = __shfl(idx, j + 3);
                ushort2 v0 = *(const ushort2*)(op_ebf + (size_t)i0 * HDIM + h);
                ushort2 v1 = *(const ushort2*)(op_ebf + (size_t)i1 * HDIM + h);
                ushort2 v2 = *(const ushort2*)(op_ebf + (size_t)i2 * HDIM + h);
                ushort2 v3 = *(const ushort2*)(op_ebf + (size_t)i3 * HDIM + h);
                a0 += bf2f(v0.x); a1 += bf2f(v0.y);
                if (j + 1 < cnt) { a0 += bf2f(v1.x); a1 += bf2f(v1.y); }
                if (j + 2 < cnt) { a0 += bf2f(v2.x); a1 += bf2f(v2.y); }
                if (j + 3 < cnt) { a0 += bf2f(v3.x); a1 += bf2f(v3.y); }
            }
        }
        float pinv = 1.f / fmaxf((float)(e0 - s0), 1.f);

        float b0 = 0.f, b1 = 0.f;
        int s1 = rs[P1 + r], e1 = rs[P1 + r + 1];
        for (int base = s1; base < e1; base += 64) {
            int cnt = min(64, e1 - base);
            int idx = (lane < cnt) ? bucket_all[base + lane] : 0;
            for (int j = 0; j < cnt; j += 4) {
                int i0 = __shfl(idx, j);
                int i1 = __shfl(idx, j + 1);
                int i2 = __shfl(idx, j + 2);
                int i3 = __shfl(idx, j + 3);
                float2 v0 = *(const float2*)(mach_emb + (size_t)i0 * HDIM + h);
                float2 v1 = *(const float2*)(mach_emb + (size_t)i1 * HDIM + h);
                float2 v2 = *(const float2*)(mach_emb + (size_t)i2 * HDIM + h);
                float2 v3 = *(const float2*)(mach_emb + (size_t)i3 * HDIM + h);
                b0 += v0.x; b1 += v0.y;
                if (j + 1 < cnt) { b0 += v1.x; b1 += v1.y; }
                if (j + 2 < cnt) { b0 += v2.x; b1 += v2.y; }
                if (j + 3 < cnt) { b0 += v3.x; b1 += v3.y; }
            }
        }
        float cinv = 1.f / fmaxf((float)(e1 - s1), 1.f);

        ushort2 pa, pb;
        pa.x = f2bf(a0 * pinv); pa.y = f2bf(a1 * pinv);
        pb.x = f2bf(b0 * cinv); pb.y = f2bf(b1 * cinv);
        *(ushort2*)(Ab + (size_t)r * 256 + h)       = pa;
        *(ushort2*)(Ab + (size_t)r * 256 + 128 + h) = pb;
        if (lane == 0) flags[r] = (e0 > s0 ? 1 : 0) | (e1 > s1 ? 2 : 0);
        return;
    }

    // ---- machine gather path: short8 rows, 4 edges per iteration, 16 groups/machine ----
    int b2 = blockIdx.x - nb_agg;
    int m  = b2 & 511;
    int yq = b2 >> 9;                 // 0..3
    int g  = lane >> 4;               // edge sub-group 0..3
    int d  = (lane & 15) * 8;         // dim base: 8 bf16 per lane
    int s0 = mach_rs[m], e0 = mach_rs[m + 1];
    float a[8];
#pragma unroll
    for (int k = 0; k < 8; ++k) a[k] = 0.f;

    // 16 groups (yq*4+wave) x 64 edges per sweep -> stride 1024
    for (int base = s0 + (yq * 4 + wave) * 64; base < e0; base += 1024) {
        int cnt = min(64, e0 - base);
        int idx = (lane < cnt) ? bucket_mach[base + lane] : 0;
        for (int j = 0; j < cnt; j += 4) {
            int jj = j + g;
            int rowi = __shfl(idx, jj);          // jj>=cnt pulls idx=0 (valid row); masked below
            short8 v = *(const short8*)(op_ebf + (size_t)rowi * HDIM + d);
            if (jj < cnt) {
#pragma unroll
                for (int k = 0; k < 8; ++k) a[k] += bf2f((unsigned short)v[k]);
            }
        }
    }
#pragma unroll
    for (int k = 0; k < 8; ++k) {
        a[k] += __shfl_xor(a[k], 16);
        a[k] += __shfl_xor(a[k], 32);
    }
    if (lane < 16) {
#pragma unroll
        for (int k = 0; k < 8; ++k)
            atomicAdd(&mach_sum[m * HDIM + d + k], a[k]);
    }
}

// ---------------- MFMA GEMM + residual + bias-flags + LayerNorm (+ optional bf16 mirror) ------
// out[r] = LN(emb[r] + A[r,0:256]@Wb^T + fp*bp + fc*bc)
// A-operand layout: A[m=lane&15][k=quad*8+j]; C/D: row=quad*4+reg, col=lane&15.
__global__ __launch_bounds__(256) void k_gemm_mfma(
    const unsigned short* __restrict__ Ab, const float* __restrict__ emb,
    const unsigned short* __restrict__ Wb,
    const float* __restrict__ bp, const float* __restrict__ bc,
    const int* __restrict__ flags,
    const float* __restrict__ g, const float* __restrict__ bt,
    float* __restrict__ dst, unsigned short* __restrict__ dstb, int M) {
    int wave = threadIdx.x >> 6, lane = threadIdx.x & 63;
    int m0 = blockIdx.x * 64 + wave * 16;
    if (m0 >= M) return;
    int quad = lane >> 4, col = lane & 15;

    floatx4 acc[8];
#pragma unroll
    for (int t = 0; t < 8; ++t) acc[t] = (floatx4){0.f, 0.f, 0.f, 0.f};

    const short* Arow  = (const short*)(Ab + (size_t)(m0 + col) * 256);
    const short* Wbase = (const short*)Wb;

#pragma unroll
    for (int ks = 0; ks < 8; ++ks) {
        short8 a = *(const short8*)(Arow + ks * 32 + quad * 8);
#pragma unroll
        for (int t = 0; t < 8; ++t) {
            short8 b = *(const short8*)(Wbase + (size_t)(t * 16 + col) * 256 + ks * 32 + quad * 8);
            acc[t] = __builtin_amdgcn_mfma_f32_16x16x32_bf16(a, b, acc[t], 0, 0, 0);
        }
    }

    float bpv[8], bcv[8], gv[8], btv[8];
#pragma unroll
    for (int t = 0; t < 8; ++t) {
        int c = t * 16 + col;
        bpv[t] = bp[c]; bcv[t] = bc[c]; gv[t] = g[c]; btv[t] = bt[c];
    }
#pragma unroll
    for (int reg = 0; reg < 4; ++reg) {
        int r = m0 + quad * 4 + reg;
        int fl = flags[r];
        float fp = (fl & 1) ? 1.f : 0.f, fc = (fl & 2) ? 1.f : 0.f;
        float x[8]; float s = 0.f, q = 0.f;
#pragma unroll
        for (int t = 0; t < 8; ++t) {
            float v = acc[t][reg] + emb[(size_t)r * HDIM + t * 16 + col] + fp * bpv[t] + fc * bcv[t];
            x[t] = v; s += v; q += v * v;
        }
#pragma unroll
        for (int msk = 1; msk < 16; msk <<= 1) { s += __shfl_xor(s, msk); q += __shfl_xor(q, msk); }
        float mu = s * (1.f / 128.f);
        float rstd = rsqrtf(fmaxf(q * (1.f / 128.f) - mu * mu, 0.f) + 1e-5f);
#pragma unroll
        for (int t = 0; t < 8; ++t) {
            float y = (x[t] - mu) * rstd * gv[t] + btv[t];
            dst[(size_t)r * HDIM + t * 16 + col] = y;
            if (dstb) dstb[(size_t)r * HDIM + t * 16 + col] = f2bf(y);
        }
    }
}

// ---------------- machine update: mean -> @Wc^T + bc -> +emb -> LN ----------------
__global__ __launch_bounds__(128) void k_mach_update(
    const float* __restrict__ mach_emb, const float* __restrict__ mach_sum,
    const int* __restrict__ mach_rs,
    const float* __restrict__ Wc, const float* __restrict__ bc,
    const float* __restrict__ g, const float* __restrict__ bt,
    float* __restrict__ dst) {
    __shared__ float row[HDIM];
    __shared__ float red[4];
    int m = blockIdx.x, t = threadIdx.x;
    int cnt = mach_rs[m + 1] - mach_rs[m];
    float sc = (cnt > 0) ? 1.f / (float)cnt : 0.f;
    row[t] = mach_sum[m * HDIM + t] * sc;
    __syncthreads();
    float dot = bc[t];
    const float* w = Wc + (size_t)t * HDIM;
#pragma unroll 8
    for (int k = 0; k < HDIM; ++k) dot += row[k] * w[k];
    float x = mach_emb[m * HDIM + t] + ((cnt > 0) ? dot : 0.f);
    float s = x, q = x * x;
#pragma unroll
    for (int o = 32; o; o >>= 1) { s += __shfl_xor(s, o); q += __shfl_xor(q, o); }
    int wv = t >> 6;
    if ((t & 63) == 0) { red[wv * 2] = s; red[wv * 2 + 1] = q; }
    __syncthreads();
    s = red[0] + red[2]; q = red[1] + red[3];
    float mu = s * (1.f / 128.f);
    float rstd = rsqrtf(fmaxf(q * (1.f / 128.f) - mu * mu, 0.f) + 1e-5f);
    dst[m * HDIM + t] = (x - mu) * rstd * g[t] + bt[t];
}

extern "C" void kernel_launch(void* const* d_in, const int* in_sizes, int n_in,
                              void* d_out, int out_size, void* d_ws, size_t ws_size,
                              hipStream_t stream) {
    const float* op_feat    = (const float*)d_in[0];
    const float* m_feat     = (const float*)d_in[1];
    const int*   prec_e     = (const int*)d_in[2];
    const int*   comp_e     = (const int*)d_in[3];
    const float* op_emb_W   = (const float*)d_in[4];
    const float* op_emb_b   = (const float*)d_in[5];
    const float* mach_emb_W = (const float*)d_in[6];
    const float* mach_emb_b = (const float*)d_in[7];
    const float* prec_W     = (const float*)d_in[8];
    const float* prec_b     = (const float*)d_in[9];
    const float* compat_W   = (const float*)d_in[10];
    const float* compat_b   = (const float*)d_in[11];
    const float* op_ln_g    = (const float*)d_in[12];
    const float* op_ln_b    = (const float*)d_in[13];
    const float* mach_ln_g  = (const float*)d_in[14];
    const float* mach_ln_b  = (const float*)d_in[15];
    float* out = (float*)d_out;

    const int M = NUM_OPS, NM = NUM_MACH;
    const int nprec = in_sizes[2] / 2;
    const int ncomp = in_sizes[3] / 2;
    const int E = ncomp / 2;   // bidirectional pairs: first half o2m, second half m2o (mirror)
    const int NT = nprec + E;

    float* ws = (float*)d_ws;
    size_t o = 0;
    float* op_emb   = ws + o; o += (size_t)M * HDIM;    // 51 MB (in-place residual+dst)
    unsigned short* op_ebf = (unsigned short*)(ws + o); o += (size_t)M * 64;   // 25.6 MB bf16 mirror
    unsigned short* Ab = (unsigned short*)(ws + o); o += (size_t)M * 128;  // 51 MB bf16 [M][256]
    unsigned short* Wb = (unsigned short*)(ws + o); o += 32768;            // 2 layers x [128][256] bf16
    float* mach_emb = ws + o; o += (size_t)NM * HDIM;
    float* mach_sum = ws + o; o += (size_t)NM * HDIM;
    int* ip = (int*)(ws + o);
    size_t io = 0;
    int* hists     = ip + io; io += NHIST + MHWORDS;  // [chist 784x256 | mach_bh 512x256]
    int* scans     = ip + io; io += NHIST + MHWORDS;  // [cscan | moff] (exclusive offsets)
    int* rs        = ip + io; io += NHIST;            // fine row starts (exclusive)
    int* mach_rs   = ip + io; io += NM + 8;
    int* partialT  = ip + io; io += 512;              // unified block sums (324 used)
    int* block_off = ip + io; io += 512;
    int* flags     = ip + io; io += M;
    int* pairs     = ip + io; io += (size_t)NT;       // coarse-partitioned packed edges
    int* bucket_all  = ip + io; io += (size_t)NT;
    int* bucket_mach = ip + io; io += (size_t)E;

    int* mach_bh = hists + NHIST;

    // ---- CSR build: two-level counting sort, 6 launches ----
    k_front<<<NBC, 256, 0, stream>>>(prec_e, nprec, comp_e, E, M, hists, mach_bh);
    k_blocksum<<<NBLK_T, 256, 0, stream>>>(hists, partialT);
    k_scanpart<<<2, 256, 0, stream>>>(partialT, block_off);
    k_scanwrite<<<NBLK_T, 256, 0, stream>>>(hists, block_off, scans);
    k_cfill<<<NBC, 256, 0, stream>>>(prec_e, nprec, comp_e, E, M, scans, pairs);
    k_finefill<<<NCOARSE + NBM, 256, 0, stream>>>(scans, NT, pairs, rs, bucket_all,
                                                  comp_e, E, M, bucket_mach, mach_rs);

    // ---- embeddings + weight conversion, one launch ----
    int prep_total = (M + NM) * HDIM + 2 * 128 * 256;
    k_prep<<<(prep_total + 255) / 256, 256, 0, stream>>>(
        op_feat, m_feat, op_emb_W, op_emb_b, mach_emb_W, mach_emb_b,
        prec_W, compat_W, op_emb, op_ebf, mach_emb, Wb);

    const int nb_agg = (M + 3) / 4;
    for (int l = 0; l < 2; ++l) {
        int last = (l == 1);
        const float* bpl = prec_b   + (size_t)l * HDIM;
        const float* Wc  = compat_W + (size_t)l * HDIM * HDIM;
        const float* bcl = compat_b + (size_t)l * HDIM;

        hipMemsetAsync(mach_sum, 0, (size_t)NM * HDIM * sizeof(float), stream);

        // merged: op-side aggregation (writes Ab/flags) + machine-side gather (atomics mach_sum)
        // reads op_ebf + mach_emb (both old); completes before gemm/mach_update overwrite them
        k_aggmg<<<nb_agg + NM * 4, 256, 0, stream>>>(
            op_ebf, mach_emb, rs, bucket_all, Ab, flags, M,
            mach_rs, bucket_mach, mach_sum, nb_agg);

        // op update (reads Ab + op_emb, overwrites op_emb + mirror in-place; stream-ordered
        // after k_aggmg's reads of the old mirror)
        k_gemm_mfma<<<(M + 63) / 64, 256, 0, stream>>>(
            Ab, op_emb, Wb + (size_t)l * 128 * 256, bpl, bcl, flags,
            op_ln_g + (size_t)l * HDIM, op_ln_b + (size_t)l * HDIM,
            last ? out : op_emb, last ? nullptr : op_ebf, M);

        // machine update (overwrites mach_emb after k_aggmg read it)
        k_mach_update<<<NM, 128, 0, stream>>>(
            mach_emb, mach_sum, mach_rs, Wc, bcl,
            mach_ln_g + (size_t)l * HDIM, mach_ln_b + (size_t)l * HDIM,
            last ? (out + (size_t)M * HDIM) : mach_emb);
    }
}

// Round 7
// 567.005 us; speedup vs baseline: 1.2920x; 1.0213x over previous
//
#include <hip/hip_runtime.h>
#include <hip/hip_bf16.h>

#define NUM_OPS   100000
#define NUM_MACH  512
#define HDIM      128
#define P1        100352            // m2o key offset (98*1024)
#define NHIST     200704            // 196*1024 == 784*256 combined key space
#define NBLK      196               // op-hist scan blocks (1024 elems each)
#define NCOARSE   784               // coarse buckets (key >> 8)
#define NBC       256               // blocks for coarse hist/fill passes
#define NBM       256               // counting-sort blocks for machine buckets
#define MHWORDS   (NUM_MACH * NBM)  // 131072 = 128*1024
#define NBLK_M    128               // machine blockhist scan blocks
#define NBLK_T    (NBLK + NBLK_M)   // 324 unified scan blocks

typedef short short8 __attribute__((ext_vector_type(8)));
typedef unsigned short ushort8 __attribute__((ext_vector_type(8)));
typedef float floatx4 __attribute__((ext_vector_type(4)));

__device__ __forceinline__ unsigned short f2bf(float f) {
    unsigned u = __float_as_uint(f);
    unsigned r = (u + 0x7FFFu + ((u >> 16) & 1u)) >> 16;   // RNE
    return (unsigned short)r;
}
__device__ __forceinline__ float bf2f(unsigned short u) {
    return __uint_as_float(((unsigned)u) << 16);
}

// ---------------- prep: op embed (bf16 mirror only) | mach embed (+bf16) | weights ------------
__global__ void k_prep(const float* __restrict__ Fo, const float* __restrict__ Fm,
                       const float* __restrict__ Wo, const float* __restrict__ bo,
                       const float* __restrict__ Wm, const float* __restrict__ bm,
                       const float* __restrict__ Wp, const float* __restrict__ Wc,
                       unsigned short* __restrict__ op_ebf,
                       float* __restrict__ mach_emb, unsigned short* __restrict__ mach_ebf,
                       unsigned short* __restrict__ Wb) {
    int idx = blockIdx.x * blockDim.x + threadIdx.x;
    if (idx < NUM_OPS * HDIM) {
        int r = idx >> 7, h = idx & 127;
        const float* f = Fo + (size_t)r * 6;
        const float* w = Wo + (size_t)h * 6;
        float s = bo[h];
#pragma unroll
        for (int i = 0; i < 6; ++i) s += f[i] * w[i];
        op_ebf[idx] = f2bf(s);
        return;
    }
    idx -= NUM_OPS * HDIM;
    if (idx < NUM_MACH * HDIM) {
        int r = idx >> 7, h = idx & 127;
        const float* f = Fm + (size_t)r * 2;
        const float* w = Wm + (size_t)h * 2;
        float s = bm[h] + f[0] * w[0] + f[1] * w[1];
        mach_emb[idx] = s;
        mach_ebf[idx] = f2bf(s);
        return;
    }
    idx -= NUM_MACH * HDIM;
    if (idx < 2 * 128 * 256) {
        int l = idx >> 15, h = (idx >> 8) & 127, k = idx & 255;
        float v = (k < 128) ? Wp[(size_t)l * 16384 + h * 128 + k]
                            : Wc[(size_t)l * 16384 + h * 128 + (k - 128)];
        Wb[idx] = f2bf(v);
    }
}

// ---------------- front: coarse op-key histogram + machine histogram (shared comp_e read) ----
// BOTH histograms chunked over unified i-space [0, NT): column j counts items in i-chunk j.
__global__ __launch_bounds__(256) void k_front(const int* __restrict__ prec_e, int nprec,
                                               const int* __restrict__ comp_e, int E, int M,
                                               int* __restrict__ chist_bh,   // [784][256]
                                               int* __restrict__ mach_bh) {  // [512][256]
    __shared__ int hc[NCOARSE];
    __shared__ int hm[NUM_MACH];
    for (int i = threadIdx.x; i < NCOARSE; i += 256) hc[i] = 0;
    for (int i = threadIdx.x; i < NUM_MACH; i += 256) hm[i] = 0;
    __syncthreads();
    int NT = nprec + E;
    int ch = (NT + NBC - 1) / NBC;
    int i0 = blockIdx.x * ch, i1 = min(NT, i0 + ch);
    for (int i = i0 + threadIdx.x; i < i1; i += 256) {
        int key;
        if (i < nprec) key = prec_e[nprec + i];
        else {
            int e = i - nprec;
            key = P1 + comp_e[e];
            atomicAdd(&hm[comp_e[E + e] - M], 1);
        }
        atomicAdd(&hc[key >> 8], 1);
    }
    __syncthreads();
    for (int i = threadIdx.x; i < NCOARSE; i += 256)
        chist_bh[i * NBC + blockIdx.x] = hc[i];
    for (int i = threadIdx.x; i < NUM_MACH; i += 256)
        mach_bh[i * NBC + blockIdx.x] = hm[i];
}

// ---------------- coarse pass B: place packed (val<<8 | key&255) via LDS cursors ----------------
__global__ __launch_bounds__(256) void k_cfill(const int* __restrict__ prec_e, int nprec,
                                               const int* __restrict__ comp_e, int E, int M,
                                               const int* __restrict__ scan,
                                               int* __restrict__ pairs) {
    __shared__ int cur[NCOARSE];
    for (int i = threadIdx.x; i < NCOARSE; i += 256) cur[i] = scan[i * NBC + blockIdx.x];
    __syncthreads();
    int NT = nprec + E;
    int ch = (NT + NBC - 1) / NBC;
    int i0 = blockIdx.x * ch, i1 = min(NT, i0 + ch);
    for (int i = i0 + threadIdx.x; i < i1; i += 256) {
        int key, val;
        if (i < nprec) { key = prec_e[nprec + i]; val = prec_e[i]; }
        else { int e = i - nprec; key = P1 + comp_e[e]; val = comp_e[E + e] - M; }
        int pos = atomicAdd(&cur[key >> 8], 1);
        pairs[pos] = (val << 8) | (key & 255);
    }
}

// ---------------- scan phase 1: per-block sums over unified [chist|mach_bh] ----------------
__global__ __launch_bounds__(256) void k_blocksum(const int* __restrict__ arr, int* __restrict__ partial) {
    __shared__ int sh[256];
    int b = blockIdx.x, t = threadIdx.x;
    int4 v = *(const int4*)(arr + b * 1024 + t * 4);
    sh[t] = v.x + v.y + v.z + v.w;
    __syncthreads();
    for (int o = 128; o; o >>= 1) { if (t < o) sh[t] += sh[t + o]; __syncthreads(); }
    if (!t) partial[b] = sh[0];
}

// ---------------- scan phase 2: two independent segments (op: 196, machine: 128) --------------
__global__ __launch_bounds__(256) void k_scanpart(const int* __restrict__ partial,
                                                  int* __restrict__ block_off) {
    __shared__ int sh[256];
    int t = threadIdx.x;
    int seg0 = blockIdx.x ? NBLK : 0;
    int n    = blockIdx.x ? NBLK_M : NBLK;
    int v = (t < n) ? partial[seg0 + t] : 0;
    sh[t] = v; __syncthreads();
    for (int o = 1; o < 256; o <<= 1) {
        int x = (t >= o) ? sh[t - o] : 0; __syncthreads();
        sh[t] += x; __syncthreads();
    }
    if (t < n) block_off[seg0 + t] = sh[t] - v;
}

// ---------------- scan phase 3: write exclusive offsets (unified) ----------------
__global__ __launch_bounds__(256) void k_scanwrite(const int* __restrict__ arr,
                                                   const int* __restrict__ block_off,
                                                   int* __restrict__ rs) {
    __shared__ int sh[256];
    int b = blockIdx.x, t = threadIdx.x;
    int base_i = b * 1024 + t * 4;
    int4 v = *(const int4*)(arr + base_i);
    int tsum = v.x + v.y + v.z + v.w;
    sh[t] = tsum; __syncthreads();
    for (int o = 1; o < 256; o <<= 1) {
        int x = (t >= o) ? sh[t - o] : 0; __syncthreads();
        sh[t] += x; __syncthreads();
    }
    int off = block_off[b] + sh[t] - tsum;
    int4 r; r.x = off; r.y = off + v.x; r.z = off + v.x + v.y; r.w = off + v.x + v.y + v.z;
    *(int4*)(rs + base_i) = r;
}

// ---------------- fine counting sort (op keys) + machine placement + mach_rs, one launch -----
// Machine branch processes the e-range of NT-chunk blk, matching k_front's columns.
__global__ __launch_bounds__(256) void k_finefill(const int* __restrict__ scans, int NT,
                                                  const int* __restrict__ pairs,
                                                  int* __restrict__ rs,
                                                  int* __restrict__ bucket_all,
                                                  const int* __restrict__ comp_e, int E, int M,
                                                  int* __restrict__ bucket_mach,
                                                  int* __restrict__ mach_rs) {
    int t = threadIdx.x;
    if (blockIdx.x < NCOARSE) {
        __shared__ int hh[256];
        __shared__ int ex[256];
        __shared__ int cu[256];
        int b = blockIdx.x;
        int s = scans[b * NBC];
        int e = (b == NCOARSE - 1) ? NT : scans[(b + 1) * NBC];
        hh[t] = 0;
        __syncthreads();
        for (int i = s + t; i < e; i += 256) atomicAdd(&hh[pairs[i] & 255], 1);
        __syncthreads();
        int v = hh[t];
        ex[t] = v; __syncthreads();
        for (int o = 1; o < 256; o <<= 1) {
            int x = (t >= o) ? ex[t - o] : 0; __syncthreads();
            ex[t] += x; __syncthreads();
        }
        int start = s + ex[t] - v;
        rs[b * 256 + t] = start;
        cu[t] = start;
        __syncthreads();
        for (int i = s + t; i < e; i += 256) {
            int p = pairs[i];
            int pos = atomicAdd(&cu[p & 255], 1);
            bucket_all[pos] = ((unsigned)p) >> 8;
        }
    } else {
        __shared__ int cur[NUM_MACH];
        int blk = blockIdx.x - NCOARSE;
        const int* moff = scans + NHIST;
        for (int i = t; i < NUM_MACH; i += 256) cur[i] = moff[i * NBM + blk];
        if (blk == 0) {
            for (int m = t; m < NUM_MACH; m += 256) mach_rs[m] = moff[m * NBM];
            if (t == 0) mach_rs[NUM_MACH] = E;
        }
        __syncthreads();
        int nprec = NT - E;
        int chNT = (NT + NBC - 1) / NBC;            // SAME chunking as k_front
        int e0 = blk * chNT - nprec;       if (e0 < 0) e0 = 0;
        int e1 = (blk + 1) * chNT - nprec; if (e1 > E) e1 = E;
        for (int e = e0 + t; e < e1; e += 256) {
            int m = comp_e[E + e] - M;
            int op = comp_e[e];
            int pos = atomicAdd(&cur[m], 1);
            bucket_mach[pos] = op;
        }
    }
}

// ---------------- shared short8 gather helper: sum bf16 rows over an edge range --------------
// 16 lanes/row (8 dims each), 4 edges per iteration; stride = step edges between sweeps.
__device__ __forceinline__ void gather8(const unsigned short* __restrict__ src,
                                        const int* __restrict__ bucket,
                                        int s0, int e0, int start, int step,
                                        int lane, int g, int d, float* a) {
    for (int base = s0 + start; base < e0; base += step) {
        int cnt = min(64, e0 - base);
        int idx = (lane < cnt) ? bucket[base + lane] : 0;
        for (int j = 0; j < cnt; j += 4) {
            int jj = j + g;
            int rowi = __shfl(idx, jj);          // jj>=cnt pulls idx=0 (valid row); masked below
            short8 v = *(const short8*)(src + (size_t)rowi * HDIM + d);
            if (jj < cnt) {
#pragma unroll
                for (int k = 0; k < 8; ++k) a[k] += bf2f((unsigned short)v[k]);
            }
        }
    }
}

// ---------------- merged per-layer aggregation: op-side gather->Ab | machine-side gather ------
// blocks [0, nb_agg): op aggregation, short8 rows: wave owns 1 op, prec (op_ebf) + m2o (mach_ebf)
// blocks [nb_agg, ...): machine gather (unchanged r6 path)
__global__ __launch_bounds__(256) void k_aggmg(
    const unsigned short* __restrict__ op_ebf, const unsigned short* __restrict__ mach_ebf,
    const int* __restrict__ rs, const int* __restrict__ bucket_all,
    unsigned short* __restrict__ Ab, int* __restrict__ flags, int M,
    const int* __restrict__ mach_rs, const int* __restrict__ bucket_mach,
    float* __restrict__ mach_sum, int nb_agg) {
    int wave = threadIdx.x >> 6, lane = threadIdx.x & 63;
    int g = lane >> 4;               // edge sub-group 0..3
    int d = (lane & 15) * 8;         // dim base: 8 bf16 per lane

    if ((int)blockIdx.x < nb_agg) {
        // ---- op aggregation path (short8) ----
        int r = blockIdx.x * 4 + wave;
        if (r >= M) return;

        float a[8];
#pragma unroll
        for (int k = 0; k < 8; ++k) a[k] = 0.f;
        int s0 = rs[r], e0 = rs[r + 1];
        gather8(op_ebf, bucket_all, s0, e0, 0, 64, lane, g, d, a);
#pragma unroll
        for (int k = 0; k < 8; ++k) {
            a[k] += __shfl_xor(a[k], 16);
            a[k] += __shfl_xor(a[k], 32);
        }
        float pinv = 1.f / fmaxf((float)(e0 - s0), 1.f);

        float b[8];
#pragma unroll
        for (int k = 0; k < 8; ++k) b[k] = 0.f;
        int s1 = rs[P1 + r], e1 = rs[P1 + r + 1];
        gather8(mach_ebf, bucket_all, s1, e1, 0, 64, lane, g, d, b);
#pragma unroll
        for (int k = 0; k < 8; ++k) {
            b[k] += __shfl_xor(b[k], 16);
            b[k] += __shfl_xor(b[k], 32);
        }
        float cinv = 1.f / fmaxf((float)(e1 - s1), 1.f);

        if (lane < 16) {
            ushort8 pa, pb;
#pragma unroll
            for (int k = 0; k < 8; ++k) { pa[k] = f2bf(a[k] * pinv); pb[k] = f2bf(b[k] * cinv); }
            *(ushort8*)(Ab + (size_t)r * 256 + d)       = pa;
            *(ushort8*)(Ab + (size_t)r * 256 + 128 + d) = pb;
        }
        if (lane == 0) flags[r] = (e0 > s0 ? 1 : 0) | (e1 > s1 ? 2 : 0);
        return;
    }

    // ---- machine gather path: short8 rows, 16 groups/machine, stride 1024 ----
    int b2 = blockIdx.x - nb_agg;
    int m  = b2 & 511;
    int yq = b2 >> 9;                 // 0..3
    int s0 = mach_rs[m], e0 = mach_rs[m + 1];
    float a[8];
#pragma unroll
    for (int k = 0; k < 8; ++k) a[k] = 0.f;
    gather8(op_ebf, bucket_mach, s0, e0, (yq * 4 + wave) * 64, 1024, lane, g, d, a);
#pragma unroll
    for (int k = 0; k < 8; ++k) {
        a[k] += __shfl_xor(a[k], 16);
        a[k] += __shfl_xor(a[k], 32);
    }
    if (lane < 16) {
#pragma unroll
        for (int k = 0; k < 8; ++k)
            atomicAdd(&mach_sum[m * HDIM + d + k], a[k]);
    }
}

// ---------------- MFMA GEMM + bf16 residual + bias-flags + LayerNorm -------------------------
// out[r] = LN(bf2f(embb[r]) + A[r,0:256]@Wb^T + fp*bp + fc*bc)
// dstf: f32 output (final layer) or null; dstb: bf16 mirror output (intermediate) or null.
// In-place embb==dstb is safe: row r is read and written only by its own 16 lanes, read-first.
__global__ __launch_bounds__(256) void k_gemm_mfma(
    const unsigned short* __restrict__ Ab, const unsigned short* __restrict__ embb,
    const unsigned short* __restrict__ Wb,
    const float* __restrict__ bp, const float* __restrict__ bc,
    const int* __restrict__ flags,
    const float* __restrict__ g, const float* __restrict__ bt,
    float* __restrict__ dstf, unsigned short* __restrict__ dstb, int M) {
    int wave = threadIdx.x >> 6, lane = threadIdx.x & 63;
    int m0 = blockIdx.x * 64 + wave * 16;
    if (m0 >= M) return;
    int quad = lane >> 4, col = lane & 15;

    floatx4 acc[8];
#pragma unroll
    for (int t = 0; t < 8; ++t) acc[t] = (floatx4){0.f, 0.f, 0.f, 0.f};

    const short* Arow  = (const short*)(Ab + (size_t)(m0 + col) * 256);
    const short* Wbase = (const short*)Wb;

#pragma unroll
    for (int ks = 0; ks < 8; ++ks) {
        short8 a = *(const short8*)(Arow + ks * 32 + quad * 8);
#pragma unroll
        for (int t = 0; t < 8; ++t) {
            short8 b = *(const short8*)(Wbase + (size_t)(t * 16 + col) * 256 + ks * 32 + quad * 8);
            acc[t] = __builtin_amdgcn_mfma_f32_16x16x32_bf16(a, b, acc[t], 0, 0, 0);
        }
    }

    float bpv[8], bcv[8], gv[8], btv[8];
#pragma unroll
    for (int t = 0; t < 8; ++t) {
        int c = t * 16 + col;
        bpv[t] = bp[c]; bcv[t] = bc[c]; gv[t] = g[c]; btv[t] = bt[c];
    }
#pragma unroll
    for (int reg = 0; reg < 4; ++reg) {
        int r = m0 + quad * 4 + reg;
        int fl = flags[r];
        float fp = (fl & 1) ? 1.f : 0.f, fc = (fl & 2) ? 1.f : 0.f;
        float x[8]; float s = 0.f, q = 0.f;
#pragma unroll
        for (int t = 0; t < 8; ++t) {
            float v = acc[t][reg] + bf2f(embb[(size_t)r * HDIM + t * 16 + col]) + fp * bpv[t] + fc * bcv[t];
            x[t] = v; s += v; q += v * v;
        }
#pragma unroll
        for (int msk = 1; msk < 16; msk <<= 1) { s += __shfl_xor(s, msk); q += __shfl_xor(q, msk); }
        float mu = s * (1.f / 128.f);
        float rstd = rsqrtf(fmaxf(q * (1.f / 128.f) - mu * mu, 0.f) + 1e-5f);
#pragma unroll
        for (int t = 0; t < 8; ++t) {
            float y = (x[t] - mu) * rstd * gv[t] + btv[t];
            if (dstf) dstf[(size_t)r * HDIM + t * 16 + col] = y;
            if (dstb) dstb[(size_t)r * HDIM + t * 16 + col] = f2bf(y);
        }
    }
}

// ---------------- machine update: mean -> @Wc^T + bc -> +emb -> LN (+ optional bf16 mirror) --
__global__ __launch_bounds__(128) void k_mach_update(
    const float* __restrict__ mach_emb, const float* __restrict__ mach_sum,
    const int* __restrict__ mach_rs,
    const float* __restrict__ Wc, const float* __restrict__ bc,
    const float* __restrict__ g, const float* __restrict__ bt,
    float* __restrict__ dst, unsigned short* __restrict__ dstb) {
    __shared__ float row[HDIM];
    __shared__ float red[4];
    int m = blockIdx.x, t = threadIdx.x;
    int cnt = mach_rs[m + 1] - mach_rs[m];
    float sc = (cnt > 0) ? 1.f / (float)cnt : 0.f;
    row[t] = mach_sum[m * HDIM + t] * sc;
    __syncthreads();
    float dot = bc[t];
    const float* w = Wc + (size_t)t * HDIM;
#pragma unroll 8
    for (int k = 0; k < HDIM; ++k) dot += row[k] * w[k];
    float x = mach_emb[m * HDIM + t] + ((cnt > 0) ? dot : 0.f);
    float s = x, q = x * x;
#pragma unroll
    for (int o = 32; o; o >>= 1) { s += __shfl_xor(s, o); q += __shfl_xor(q, o); }
    int wv = t >> 6;
    if ((t & 63) == 0) { red[wv * 2] = s; red[wv * 2 + 1] = q; }
    __syncthreads();
    s = red[0] + red[2]; q = red[1] + red[3];
    float mu = s * (1.f / 128.f);
    float rstd = rsqrtf(fmaxf(q * (1.f / 128.f) - mu * mu, 0.f) + 1e-5f);
    float y = (x - mu) * rstd * g[t] + bt[t];
    dst[m * HDIM + t] = y;
    if (dstb) dstb[m * HDIM + t] = f2bf(y);
}

extern "C" void kernel_launch(void* const* d_in, const int* in_sizes, int n_in,
                              void* d_out, int out_size, void* d_ws, size_t ws_size,
                              hipStream_t stream) {
    const float* op_feat    = (const float*)d_in[0];
    const float* m_feat     = (const float*)d_in[1];
    const int*   prec_e     = (const int*)d_in[2];
    const int*   comp_e     = (const int*)d_in[3];
    const float* op_emb_W   = (const float*)d_in[4];
    const float* op_emb_b   = (const float*)d_in[5];
    const float* mach_emb_W = (const float*)d_in[6];
    const float* mach_emb_b = (const float*)d_in[7];
    const float* prec_W     = (const float*)d_in[8];
    const float* prec_b     = (const float*)d_in[9];
    const float* compat_W   = (const float*)d_in[10];
    const float* compat_b   = (const float*)d_in[11];
    const float* op_ln_g    = (const float*)d_in[12];
    const float* op_ln_b    = (const float*)d_in[13];
    const float* mach_ln_g  = (const float*)d_in[14];
    const float* mach_ln_b  = (const float*)d_in[15];
    float* out = (float*)d_out;

    const int M = NUM_OPS, NM = NUM_MACH;
    const int nprec = in_sizes[2] / 2;
    const int ncomp = in_sizes[3] / 2;
    const int E = ncomp / 2;   // bidirectional pairs: first half o2m, second half m2o (mirror)
    const int NT = nprec + E;

    float* ws = (float*)d_ws;
    size_t o = 0;
    unsigned short* op_ebf = (unsigned short*)(ws + o); o += (size_t)M * 64;   // 25.6 MB bf16 state
    unsigned short* Ab = (unsigned short*)(ws + o); o += (size_t)M * 128;  // 51 MB bf16 [M][256]
    unsigned short* Wb = (unsigned short*)(ws + o); o += 32768;            // 2 layers x [128][256] bf16
    float* mach_emb = ws + o; o += (size_t)NM * HDIM;
    unsigned short* mach_ebf = (unsigned short*)(ws + o); o += (size_t)NM * 64;
    float* mach_sum = ws + o; o += (size_t)NM * HDIM;
    int* ip = (int*)(ws + o);
    size_t io = 0;
    int* hists     = ip + io; io += NHIST + MHWORDS;  // [chist 784x256 | mach_bh 512x256]
    int* scans     = ip + io; io += NHIST + MHWORDS;  // [cscan | moff] (exclusive offsets)
    int* rs        = ip + io; io += NHIST;            // fine row starts (exclusive)
    int* mach_rs   = ip + io; io += NM + 8;
    int* partialT  = ip + io; io += 512;              // unified block sums (324 used)
    int* block_off = ip + io; io += 512;
    int* flags     = ip + io; io += M;
    int* pairs     = ip + io; io += (size_t)NT;       // coarse-partitioned packed edges
    int* bucket_all  = ip + io; io += (size_t)NT;
    int* bucket_mach = ip + io; io += (size_t)E;

    int* mach_bh = hists + NHIST;

    // ---- CSR build: two-level counting sort, 6 launches ----
    k_front<<<NBC, 256, 0, stream>>>(prec_e, nprec, comp_e, E, M, hists, mach_bh);
    k_blocksum<<<NBLK_T, 256, 0, stream>>>(hists, partialT);
    k_scanpart<<<2, 256, 0, stream>>>(partialT, block_off);
    k_scanwrite<<<NBLK_T, 256, 0, stream>>>(hists, block_off, scans);
    k_cfill<<<NBC, 256, 0, stream>>>(prec_e, nprec, comp_e, E, M, scans, pairs);
    k_finefill<<<NCOARSE + NBM, 256, 0, stream>>>(scans, NT, pairs, rs, bucket_all,
                                                  comp_e, E, M, bucket_mach, mach_rs);

    // ---- embeddings + weight conversion, one launch ----
    int prep_total = (M + NM) * HDIM + 2 * 128 * 256;
    k_prep<<<(prep_total + 255) / 256, 256, 0, stream>>>(
        op_feat, m_feat, op_emb_W, op_emb_b, mach_emb_W, mach_emb_b,
        prec_W, compat_W, op_ebf, mach_emb, mach_ebf, Wb);

    const int nb_agg = (M + 3) / 4;
    for (int l = 0; l < 2; ++l) {
        int last = (l == 1);
        const float* bpl = prec_b   + (size_t)l * HDIM;
        const float* Wc  = compat_W + (size_t)l * HDIM * HDIM;
        const float* bcl = compat_b + (size_t)l * HDIM;

        hipMemsetAsync(mach_sum, 0, (size_t)NM * HDIM * sizeof(float), stream);

        // merged: op-side aggregation (writes Ab/flags) + machine-side gather (atomics mach_sum)
        // reads op_ebf + mach_ebf (both old); completes before updates overwrite them
        k_aggmg<<<nb_agg + NM * 4, 256, 0, stream>>>(
            op_ebf, mach_ebf, rs, bucket_all, Ab, flags, M,
            mach_rs, bucket_mach, mach_sum, nb_agg);

        // op update: reads Ab + bf16 residual, writes bf16 state in-place (or f32 out at last)
        k_gemm_mfma<<<(M + 63) / 64, 256, 0, stream>>>(
            Ab, op_ebf, Wb + (size_t)l * 128 * 256, bpl, bcl, flags,
            op_ln_g + (size_t)l * HDIM, op_ln_b + (size_t)l * HDIM,
            last ? out : nullptr, last ? nullptr : op_ebf, M);

        // machine update (overwrites mach_emb/mach_ebf after k_aggmg read them)
        k_mach_update<<<NM, 128, 0, stream>>>(
            mach_emb, mach_sum, mach_rs, Wc, bcl,
            mach_ln_g + (size_t)l * HDIM, mach_ln_b + (size_t)l * HDIM,
            last ? (out + (size_t)M * HDIM) : mach_emb, last ? nullptr : mach_ebf);
    }
}

// Round 8
// 561.326 us; speedup vs baseline: 1.3051x; 1.0101x over previous
//
#include <hip/hip_runtime.h>
#include <hip/hip_bf16.h>

#define NUM_OPS   100000
#define NUM_MACH  512
#define HDIM      128
#define P1        100352            // m2o key offset (98*1024)
#define NHIST     200704            // 196*1024 == 784*256 combined key space
#define NBLK      196               // op-hist scan blocks (1024 elems each)
#define NCOARSE   784               // coarse buckets (key >> 8)
#define NBC       256               // blocks for coarse hist/fill passes
#define NBM       256               // counting-sort blocks for machine buckets
#define MHWORDS   (NUM_MACH * NBM)  // 131072 = 128*1024
#define NBLK_M    128               // machine blockhist scan blocks
#define NBLK_T    (NBLK + NBLK_M)   // 324 unified scan blocks
#define NB_OP     (NUM_OPS / 16)    // 6250 fused op blocks (16 rows each)

typedef short short8 __attribute__((ext_vector_type(8)));
typedef unsigned short ushort8 __attribute__((ext_vector_type(8)));
typedef float floatx4 __attribute__((ext_vector_type(4)));

__device__ __forceinline__ unsigned short f2bf(float f) {
    unsigned u = __float_as_uint(f);
    unsigned r = (u + 0x7FFFu + ((u >> 16) & 1u)) >> 16;   // RNE
    return (unsigned short)r;
}
__device__ __forceinline__ float bf2f(unsigned short u) {
    return __uint_as_float(((unsigned)u) << 16);
}

// ---------------- prep: op embed (bf16) | mach embed (+bf16) | weights ------------
__global__ void k_prep(const float* __restrict__ Fo, const float* __restrict__ Fm,
                       const float* __restrict__ Wo, const float* __restrict__ bo,
                       const float* __restrict__ Wm, const float* __restrict__ bm,
                       const float* __restrict__ Wp, const float* __restrict__ Wc,
                       unsigned short* __restrict__ op_ebf,
                       float* __restrict__ mach_emb, unsigned short* __restrict__ mach_ebf,
                       unsigned short* __restrict__ Wb) {
    int idx = blockIdx.x * blockDim.x + threadIdx.x;
    if (idx < NUM_OPS * HDIM) {
        int r = idx >> 7, h = idx & 127;
        const float* f = Fo + (size_t)r * 6;
        const float* w = Wo + (size_t)h * 6;
        float s = bo[h];
#pragma unroll
        for (int i = 0; i < 6; ++i) s += f[i] * w[i];
        op_ebf[idx] = f2bf(s);
        return;
    }
    idx -= NUM_OPS * HDIM;
    if (idx < NUM_MACH * HDIM) {
        int r = idx >> 7, h = idx & 127;
        const float* f = Fm + (size_t)r * 2;
        const float* w = Wm + (size_t)h * 2;
        float s = bm[h] + f[0] * w[0] + f[1] * w[1];
        mach_emb[idx] = s;
        mach_ebf[idx] = f2bf(s);
        return;
    }
    idx -= NUM_MACH * HDIM;
    if (idx < 2 * 128 * 256) {
        int l = idx >> 15, h = (idx >> 8) & 127, k = idx & 255;
        float v = (k < 128) ? Wp[(size_t)l * 16384 + h * 128 + k]
                            : Wc[(size_t)l * 16384 + h * 128 + (k - 128)];
        Wb[idx] = f2bf(v);
    }
}

// ---------------- front: coarse op-key histogram + machine histogram (shared comp_e read) ----
// BOTH histograms chunked over unified i-space [0, NT): column j counts items in i-chunk j.
__global__ __launch_bounds__(256) void k_front(const int* __restrict__ prec_e, int nprec,
                                               const int* __restrict__ comp_e, int E, int M,
                                               int* __restrict__ chist_bh,   // [784][256]
                                               int* __restrict__ mach_bh) {  // [512][256]
    __shared__ int hc[NCOARSE];
    __shared__ int hm[NUM_MACH];
    for (int i = threadIdx.x; i < NCOARSE; i += 256) hc[i] = 0;
    for (int i = threadIdx.x; i < NUM_MACH; i += 256) hm[i] = 0;
    __syncthreads();
    int NT = nprec + E;
    int ch = (NT + NBC - 1) / NBC;
    int i0 = blockIdx.x * ch, i1 = min(NT, i0 + ch);
    for (int i = i0 + threadIdx.x; i < i1; i += 256) {
        int key;
        if (i < nprec) key = prec_e[nprec + i];
        else {
            int e = i - nprec;
            key = P1 + comp_e[e];
            atomicAdd(&hm[comp_e[E + e] - M], 1);
        }
        atomicAdd(&hc[key >> 8], 1);
    }
    __syncthreads();
    for (int i = threadIdx.x; i < NCOARSE; i += 256)
        chist_bh[i * NBC + blockIdx.x] = hc[i];
    for (int i = threadIdx.x; i < NUM_MACH; i += 256)
        mach_bh[i * NBC + blockIdx.x] = hm[i];
}

// ---------------- coarse pass B: place packed (val<<8 | key&255) via LDS cursors ----------------
__global__ __launch_bounds__(256) void k_cfill(const int* __restrict__ prec_e, int nprec,
                                               const int* __restrict__ comp_e, int E, int M,
                                               const int* __restrict__ scan,
                                               int* __restrict__ pairs) {
    __shared__ int cur[NCOARSE];
    for (int i = threadIdx.x; i < NCOARSE; i += 256) cur[i] = scan[i * NBC + blockIdx.x];
    __syncthreads();
    int NT = nprec + E;
    int ch = (NT + NBC - 1) / NBC;
    int i0 = blockIdx.x * ch, i1 = min(NT, i0 + ch);
    for (int i = i0 + threadIdx.x; i < i1; i += 256) {
        int key, val;
        if (i < nprec) { key = prec_e[nprec + i]; val = prec_e[i]; }
        else { int e = i - nprec; key = P1 + comp_e[e]; val = comp_e[E + e] - M; }
        int pos = atomicAdd(&cur[key >> 8], 1);
        pairs[pos] = (val << 8) | (key & 255);
    }
}

// ---------------- scan phase 1: per-block sums over unified [chist|mach_bh] ----------------
__global__ __launch_bounds__(256) void k_blocksum(const int* __restrict__ arr, int* __restrict__ partial) {
    __shared__ int sh[256];
    int b = blockIdx.x, t = threadIdx.x;
    int4 v = *(const int4*)(arr + b * 1024 + t * 4);
    sh[t] = v.x + v.y + v.z + v.w;
    __syncthreads();
    for (int o = 128; o; o >>= 1) { if (t < o) sh[t] += sh[t + o]; __syncthreads(); }
    if (!t) partial[b] = sh[0];
}

// ---------------- scan phase 2: two independent segments (op: 196, machine: 128) --------------
__global__ __launch_bounds__(256) void k_scanpart(const int* __restrict__ partial,
                                                  int* __restrict__ block_off) {
    __shared__ int sh[256];
    int t = threadIdx.x;
    int seg0 = blockIdx.x ? NBLK : 0;
    int n    = blockIdx.x ? NBLK_M : NBLK;
    int v = (t < n) ? partial[seg0 + t] : 0;
    sh[t] = v; __syncthreads();
    for (int o = 1; o < 256; o <<= 1) {
        int x = (t >= o) ? sh[t - o] : 0; __syncthreads();
        sh[t] += x; __syncthreads();
    }
    if (t < n) block_off[seg0 + t] = sh[t] - v;
}

// ---------------- scan phase 3: write exclusive offsets (unified) ----------------
__global__ __launch_bounds__(256) void k_scanwrite(const int* __restrict__ arr,
                                                   const int* __restrict__ block_off,
                                                   int* __restrict__ rs) {
    __shared__ int sh[256];
    int b = blockIdx.x, t = threadIdx.x;
    int base_i = b * 1024 + t * 4;
    int4 v = *(const int4*)(arr + base_i);
    int tsum = v.x + v.y + v.z + v.w;
    sh[t] = tsum; __syncthreads();
    for (int o = 1; o < 256; o <<= 1) {
        int x = (t >= o) ? sh[t - o] : 0; __syncthreads();
        sh[t] += x; __syncthreads();
    }
    int off = block_off[b] + sh[t] - tsum;
    int4 r; r.x = off; r.y = off + v.x; r.z = off + v.x + v.y; r.w = off + v.x + v.y + v.z;
    *(int4*)(rs + base_i) = r;
}

// ---------------- fine counting sort (op keys) + machine placement + mach_rs, one launch -----
// Machine branch processes the e-range of NT-chunk blk, matching k_front's columns.
__global__ __launch_bounds__(256) void k_finefill(const int* __restrict__ scans, int NT,
                                                  const int* __restrict__ pairs,
                                                  int* __restrict__ rs,
                                                  int* __restrict__ bucket_all,
                                                  const int* __restrict__ comp_e, int E, int M,
                                                  int* __restrict__ bucket_mach,
                                                  int* __restrict__ mach_rs) {
    int t = threadIdx.x;
    if (blockIdx.x < NCOARSE) {
        __shared__ int hh[256];
        __shared__ int ex[256];
        __shared__ int cu[256];
        int b = blockIdx.x;
        int s = scans[b * NBC];
        int e = (b == NCOARSE - 1) ? NT : scans[(b + 1) * NBC];
        hh[t] = 0;
        __syncthreads();
        for (int i = s + t; i < e; i += 256) atomicAdd(&hh[pairs[i] & 255], 1);
        __syncthreads();
        int v = hh[t];
        ex[t] = v; __syncthreads();
        for (int o = 1; o < 256; o <<= 1) {
            int x = (t >= o) ? ex[t - o] : 0; __syncthreads();
            ex[t] += x; __syncthreads();
        }
        int start = s + ex[t] - v;
        rs[b * 256 + t] = start;
        cu[t] = start;
        __syncthreads();
        for (int i = s + t; i < e; i += 256) {
            int p = pairs[i];
            int pos = atomicAdd(&cu[p & 255], 1);
            bucket_all[pos] = ((unsigned)p) >> 8;
        }
    } else {
        __shared__ int cur[NUM_MACH];
        int blk = blockIdx.x - NCOARSE;
        const int* moff = scans + NHIST;
        for (int i = t; i < NUM_MACH; i += 256) cur[i] = moff[i * NBM + blk];
        if (blk == 0) {
            for (int m = t; m < NUM_MACH; m += 256) mach_rs[m] = moff[m * NBM];
            if (t == 0) mach_rs[NUM_MACH] = E;
        }
        __syncthreads();
        int nprec = NT - E;
        int chNT = (NT + NBC - 1) / NBC;            // SAME chunking as k_front
        int e0 = blk * chNT - nprec;       if (e0 < 0) e0 = 0;
        int e1 = (blk + 1) * chNT - nprec; if (e1 > E) e1 = E;
        for (int e = e0 + t; e < e1; e += 256) {
            int m = comp_e[E + e] - M;
            int op = comp_e[e];
            int pos = atomicAdd(&cur[m], 1);
            bucket_mach[pos] = op;
        }
    }
}

// ---------------- shared short8 gather helper: sum bf16 rows over an edge range --------------
__device__ __forceinline__ void gather8(const unsigned short* __restrict__ src,
                                        const int* __restrict__ bucket,
                                        int s0, int e0, int start, int step,
                                        int lane, int g, int d, float* a) {
    for (int base = s0 + start; base < e0; base += step) {
        int cnt = min(64, e0 - base);
        int idx = (lane < cnt) ? bucket[base + lane] : 0;
        for (int j = 0; j < cnt; j += 4) {
            int jj = j + g;
            int rowi = __shfl(idx, jj);          // jj>=cnt pulls idx=0 (valid row); masked below
            short8 v = *(const short8*)(src + (size_t)rowi * HDIM + d);
            if (jj < cnt) {
#pragma unroll
                for (int k = 0; k < 8; ++k) a[k] += bf2f((unsigned short)v[k]);
            }
        }
    }
}

// ---------------- FUSED per-layer op update + machine gather, one launch --------------------
// blocks [0, NB_OP): 16 waves; phase1: wave w aggregates row r=b*16+w (prec + m2o means) into
//   XOR-swizzled LDS A-tile (1 row/wave -> full gather TLP, r3 lesson). phase2: waves 0-7 each
//   compute one 16x16 output t-block via MFMA, raw acc -> LDS Xt. phase3: wave w does row w's
//   residual + bias-flags + LayerNorm over 128 cols and stores f32/bf16.
// blocks [NB_OP, NB_OP+NUM_MACH): machine gather, 16 waves = 16 edge-groups (stride 1024).
// Reads old ebf_src/mach_ebf; writes ebf_dst (ping-pong) -> no in-place race.
__global__ __launch_bounds__(1024, 8) void k_fused(
    const unsigned short* __restrict__ ebf_src, const unsigned short* __restrict__ mach_ebf,
    const int* __restrict__ rs, const int* __restrict__ bucket_all,
    const unsigned short* __restrict__ Wb,
    const float* __restrict__ bp, const float* __restrict__ bc,
    const float* __restrict__ g, const float* __restrict__ bt,
    float* __restrict__ dstf, unsigned short* __restrict__ dstb,
    const int* __restrict__ mach_rs, const int* __restrict__ bucket_mach,
    float* __restrict__ mach_sum, int M) {
    __shared__ unsigned short At[16 * 256];   // 8 KB, rows 512 B, chunk-swizzled
    __shared__ float Xt[16][HDIM];            // 8 KB raw MFMA output
    __shared__ int flg[16];
    int wave = threadIdx.x >> 6, lane = threadIdx.x & 63;
    int gg = lane >> 4;               // edge sub-group 0..3
    int d  = (lane & 15) * 8;         // dim base: 8 bf16 per lane

    if ((int)blockIdx.x >= NB_OP) {
        // ---- machine gather: 16 waves = 16 groups of 64 edges, stride 1024 ----
        int m = blockIdx.x - NB_OP;
        int s0 = mach_rs[m], e0 = mach_rs[m + 1];
        float a[8];
#pragma unroll
        for (int k = 0; k < 8; ++k) a[k] = 0.f;
        gather8(ebf_src, bucket_mach, s0, e0, wave * 64, 1024, lane, gg, d, a);
#pragma unroll
        for (int k = 0; k < 8; ++k) {
            a[k] += __shfl_xor(a[k], 16);
            a[k] += __shfl_xor(a[k], 32);
        }
        if (lane < 16) {
#pragma unroll
            for (int k = 0; k < 8; ++k)
                atomicAdd(&mach_sum[m * HDIM + d + k], a[k]);
        }
        return;
    }

    // ---- phase 1: per-wave single-row aggregation -> swizzled LDS A-tile ----
    int r = blockIdx.x * 16 + wave;
    {
        float a[8];
#pragma unroll
        for (int k = 0; k < 8; ++k) a[k] = 0.f;
        int s0 = rs[r], e0 = rs[r + 1];
        gather8(ebf_src, bucket_all, s0, e0, 0, 64, lane, gg, d, a);
#pragma unroll
        for (int k = 0; k < 8; ++k) {
            a[k] += __shfl_xor(a[k], 16);
            a[k] += __shfl_xor(a[k], 32);
        }
        float pinv = 1.f / fmaxf((float)(e0 - s0), 1.f);

        float b[8];
#pragma unroll
        for (int k = 0; k < 8; ++k) b[k] = 0.f;
        int s1 = rs[P1 + r], e1 = rs[P1 + r + 1];
        gather8(mach_ebf, bucket_all, s1, e1, 0, 64, lane, gg, d, b);
#pragma unroll
        for (int k = 0; k < 8; ++k) {
            b[k] += __shfl_xor(b[k], 16);
            b[k] += __shfl_xor(b[k], 32);
        }
        float cinv = 1.f / fmaxf((float)(e1 - s1), 1.f);

        if (lane < 16) {
            ushort8 pa, pb;
#pragma unroll
            for (int k = 0; k < 8; ++k) { pa[k] = f2bf(a[k] * pinv); pb[k] = f2bf(b[k] * cinv); }
            unsigned sw = (wave & 7) << 4;
            *(ushort8*)((char*)At + wave * 512 + ((lane * 16) ^ sw))         = pa;
            *(ushort8*)((char*)At + wave * 512 + (256 + ((lane * 16) ^ sw))) = pb;
        }
        if (lane == 0) flg[wave] = (e0 > s0 ? 1 : 0) | (e1 > s1 ? 2 : 0);
    }
    __syncthreads();

    // ---- phase 2: waves 0-7, each one 16x16 t-block of the 16x256 @ Wb^T MFMA ----
    if (wave < 8) {
        int t = wave, quad = lane >> 4, col = lane & 15;
        unsigned swr = (col & 7) << 4;
        floatx4 acc = (floatx4){0.f, 0.f, 0.f, 0.f};
        const short* Wrow = (const short*)Wb + (size_t)(t * 16 + col) * 256;
#pragma unroll
        for (int ks = 0; ks < 8; ++ks) {
            short8 af = *(const short8*)((const char*)At + col * 512 + ((ks * 64 + quad * 16) ^ swr));
            short8 bf = *(const short8*)(Wrow + ks * 32 + quad * 8);
            acc = __builtin_amdgcn_mfma_f32_16x16x32_bf16(af, bf, acc, 0, 0, 0);
        }
        // C/D layout: row = quad*4+reg, col' = lane&15
#pragma unroll
        for (int reg = 0; reg < 4; ++reg)
            Xt[quad * 4 + reg][t * 16 + col] = acc[reg];
    }
    __syncthreads();

    // ---- phase 3: wave w -> row w: residual + bias-flags + LN over 128 cols, store ----
    {
        int row = wave;
        int rr = blockIdx.x * 16 + row;
        int c = lane * 2;
        int fl = flg[row];
        float fp = (fl & 1) ? 1.f : 0.f, fc = (fl & 2) ? 1.f : 0.f;
        ushort2 e2 = *(const ushort2*)(ebf_src + (size_t)rr * HDIM + c);
        float2 bpv = *(const float2*)(bp + c);
        float2 bcv = *(const float2*)(bc + c);
        float x0 = Xt[row][c]     + bf2f(e2.x) + fp * bpv.x + fc * bcv.x;
        float x1 = Xt[row][c + 1] + bf2f(e2.y) + fp * bpv.y + fc * bcv.y;
        float s = x0 + x1, q = x0 * x0 + x1 * x1;
#pragma unroll
        for (int o = 32; o; o >>= 1) { s += __shfl_xor(s, o); q += __shfl_xor(q, o); }
        float mu = s * (1.f / 128.f);
        float rstd = rsqrtf(fmaxf(q * (1.f / 128.f) - mu * mu, 0.f) + 1e-5f);
        float2 gv = *(const float2*)(g + c);
        float2 bv = *(const float2*)(bt + c);
        float y0 = (x0 - mu) * rstd * gv.x + bv.x;
        float y1 = (x1 - mu) * rstd * gv.y + bv.y;
        if (dstf) { float2 yy; yy.x = y0; yy.y = y1; *(float2*)(dstf + (size_t)rr * HDIM + c) = yy; }
        if (dstb) { ushort2 ys; ys.x = f2bf(y0); ys.y = f2bf(y1); *(ushort2*)(dstb + (size_t)rr * HDIM + c) = ys; }
    }
}

// ---------------- machine update: mean -> @Wc^T + bc -> +emb -> LN (+ optional bf16 mirror) --
__global__ __launch_bounds__(128) void k_mach_update(
    const float* __restrict__ mach_emb, const float* __restrict__ mach_sum,
    const int* __restrict__ mach_rs,
    const float* __restrict__ Wc, const float* __restrict__ bc,
    const float* __restrict__ g, const float* __restrict__ bt,
    float* __restrict__ dst, unsigned short* __restrict__ dstb) {
    __shared__ float row[HDIM];
    __shared__ float red[4];
    int m = blockIdx.x, t = threadIdx.x;
    int cnt = mach_rs[m + 1] - mach_rs[m];
    float sc = (cnt > 0) ? 1.f / (float)cnt : 0.f;
    row[t] = mach_sum[m * HDIM + t] * sc;
    __syncthreads();
    float dot = bc[t];
    const float* w = Wc + (size_t)t * HDIM;
#pragma unroll 8
    for (int k = 0; k < HDIM; ++k) dot += row[k] * w[k];
    float x = mach_emb[m * HDIM + t] + ((cnt > 0) ? dot : 0.f);
    float s = x, q = x * x;
#pragma unroll
    for (int o = 32; o; o >>= 1) { s += __shfl_xor(s, o); q += __shfl_xor(q, o); }
    int wv = t >> 6;
    if ((t & 63) == 0) { red[wv * 2] = s; red[wv * 2 + 1] = q; }
    __syncthreads();
    s = red[0] + red[2]; q = red[1] + red[3];
    float mu = s * (1.f / 128.f);
    float rstd = rsqrtf(fmaxf(q * (1.f / 128.f) - mu * mu, 0.f) + 1e-5f);
    float y = (x - mu) * rstd * g[t] + bt[t];
    dst[m * HDIM + t] = y;
    if (dstb) dstb[m * HDIM + t] = f2bf(y);
}

extern "C" void kernel_launch(void* const* d_in, const int* in_sizes, int n_in,
                              void* d_out, int out_size, void* d_ws, size_t ws_size,
                              hipStream_t stream) {
    const float* op_feat    = (const float*)d_in[0];
    const float* m_feat     = (const float*)d_in[1];
    const int*   prec_e     = (const int*)d_in[2];
    const int*   comp_e     = (const int*)d_in[3];
    const float* op_emb_W   = (const float*)d_in[4];
    const float* op_emb_b   = (const float*)d_in[5];
    const float* mach_emb_W = (const float*)d_in[6];
    const float* mach_emb_b = (const float*)d_in[7];
    const float* prec_W     = (const float*)d_in[8];
    const float* prec_b     = (const float*)d_in[9];
    const float* compat_W   = (const float*)d_in[10];
    const float* compat_b   = (const float*)d_in[11];
    const float* op_ln_g    = (const float*)d_in[12];
    const float* op_ln_b    = (const float*)d_in[13];
    const float* mach_ln_g  = (const float*)d_in[14];
    const float* mach_ln_b  = (const float*)d_in[15];
    float* out = (float*)d_out;

    const int M = NUM_OPS, NM = NUM_MACH;
    const int nprec = in_sizes[2] / 2;
    const int ncomp = in_sizes[3] / 2;
    const int E = ncomp / 2;   // bidirectional pairs: first half o2m, second half m2o (mirror)
    const int NT = nprec + E;

    float* ws = (float*)d_ws;
    size_t o = 0;
    unsigned short* op_ebfA = (unsigned short*)(ws + o); o += (size_t)M * 64;  // 25.6 MB bf16 state A
    unsigned short* op_ebfB = (unsigned short*)(ws + o); o += (size_t)M * 64;  // 25.6 MB bf16 state B
    unsigned short* Wb = (unsigned short*)(ws + o); o += 32768;            // 2 layers x [128][256] bf16
    float* mach_emb = ws + o; o += (size_t)NM * HDIM;
    unsigned short* mach_ebf = (unsigned short*)(ws + o); o += (size_t)NM * 64;
    float* mach_sum = ws + o; o += (size_t)NM * HDIM;
    int* ip = (int*)(ws + o);
    size_t io = 0;
    int* hists     = ip + io; io += NHIST + MHWORDS;  // [chist 784x256 | mach_bh 512x256]
    int* scans     = ip + io; io += NHIST + MHWORDS;  // [cscan | moff] (exclusive offsets)
    int* rs        = ip + io; io += NHIST;            // fine row starts (exclusive)
    int* mach_rs   = ip + io; io += NM + 8;
    int* partialT  = ip + io; io += 512;              // unified block sums (324 used)
    int* block_off = ip + io; io += 512;
    int* pairs     = ip + io; io += (size_t)NT;       // coarse-partitioned packed edges
    int* bucket_all  = ip + io; io += (size_t)NT;
    int* bucket_mach = ip + io; io += (size_t)E;

    int* mach_bh = hists + NHIST;

    // ---- CSR build: two-level counting sort, 6 launches ----
    k_front<<<NBC, 256, 0, stream>>>(prec_e, nprec, comp_e, E, M, hists, mach_bh);
    k_blocksum<<<NBLK_T, 256, 0, stream>>>(hists, partialT);
    k_scanpart<<<2, 256, 0, stream>>>(partialT, block_off);
    k_scanwrite<<<NBLK_T, 256, 0, stream>>>(hists, block_off, scans);
    k_cfill<<<NBC, 256, 0, stream>>>(prec_e, nprec, comp_e, E, M, scans, pairs);
    k_finefill<<<NCOARSE + NBM, 256, 0, stream>>>(scans, NT, pairs, rs, bucket_all,
                                                  comp_e, E, M, bucket_mach, mach_rs);

    // ---- embeddings + weight conversion, one launch ----
    int prep_total = (M + NM) * HDIM + 2 * 128 * 256;
    k_prep<<<(prep_total + 255) / 256, 256, 0, stream>>>(
        op_feat, m_feat, op_emb_W, op_emb_b, mach_emb_W, mach_emb_b,
        prec_W, compat_W, op_ebfA, mach_emb, mach_ebf, Wb);

    for (int l = 0; l < 2; ++l) {
        int last = (l == 1);
        const unsigned short* ebf_src = last ? op_ebfB : op_ebfA;
        unsigned short* ebf_dst = last ? nullptr : op_ebfB;
        const float* bpl = prec_b   + (size_t)l * HDIM;
        const float* Wc  = compat_W + (size_t)l * HDIM * HDIM;
        const float* bcl = compat_b + (size_t)l * HDIM;

        hipMemsetAsync(mach_sum, 0, (size_t)NM * HDIM * sizeof(float), stream);

        // fused: op agg+GEMM+LN (ping-pong bf16 state) | machine gather (atomics mach_sum)
        k_fused<<<NB_OP + NM, 1024, 0, stream>>>(
            ebf_src, mach_ebf, rs, bucket_all,
            Wb + (size_t)l * 128 * 256, bpl, bcl,
            op_ln_g + (size_t)l * HDIM, op_ln_b + (size_t)l * HDIM,
            last ? out : nullptr, ebf_dst,
            mach_rs, bucket_mach, mach_sum, M);

        // machine update (overwrites mach_emb/mach_ebf after k_fused read them)
        k_mach_update<<<NM, 128, 0, stream>>>(
            mach_emb, mach_sum, mach_rs, Wc, bcl,
            mach_ln_g + (size_t)l * HDIM, mach_ln_b + (size_t)l * HDIM,
            last ? (out + (size_t)M * HDIM) : mach_emb, last ? nullptr : mach_ebf);
    }
}

// Round 9
// 539.273 us; speedup vs baseline: 1.3585x; 1.0409x over previous
//
#include <hip/hip_runtime.h>
#include <hip/hip_bf16.h>

#define NUM_OPS   100000
#define NUM_MACH  512
#define HDIM      128
#define P1        100352            // m2o key offset (98*1024)
#define NHIST     200704            // 196*1024 == 784*256 combined key space
#define NBLK      196               // op-hist scan blocks (1024 elems each)
#define NCOARSE   784               // coarse buckets (key >> 8)
#define NBC       256               // blocks for coarse hist/fill passes
#define NBM       256               // counting-sort blocks for machine buckets
#define MHWORDS   (NUM_MACH * NBM)  // 131072 = 128*1024
#define NBLK_M    128               // machine blockhist scan blocks
#define NBLK_T    (NBLK + NBLK_M)   // 324 unified scan blocks

typedef short short8 __attribute__((ext_vector_type(8)));
typedef unsigned short ushort8 __attribute__((ext_vector_type(8)));
typedef float floatx4 __attribute__((ext_vector_type(4)));

__device__ __forceinline__ unsigned short f2bf(float f) {
    unsigned u = __float_as_uint(f);
    unsigned r = (u + 0x7FFFu + ((u >> 16) & 1u)) >> 16;   // RNE
    return (unsigned short)r;
}
__device__ __forceinline__ float bf2f(unsigned short u) {
    return __uint_as_float(((unsigned)u) << 16);
}

// ---------------- prep: op embed (bf16) | mach embed (+bf16) | weights ------------
__global__ void k_prep(const float* __restrict__ Fo, const float* __restrict__ Fm,
                       const float* __restrict__ Wo, const float* __restrict__ bo,
                       const float* __restrict__ Wm, const float* __restrict__ bm,
                       const float* __restrict__ Wp, const float* __restrict__ Wc,
                       unsigned short* __restrict__ op_ebf,
                       float* __restrict__ mach_emb, unsigned short* __restrict__ mach_ebf,
                       unsigned short* __restrict__ Wb) {
    int idx = blockIdx.x * blockDim.x + threadIdx.x;
    if (idx < NUM_OPS * HDIM) {
        int r = idx >> 7, h = idx & 127;
        const float* f = Fo + (size_t)r * 6;
        const float* w = Wo + (size_t)h * 6;
        float s = bo[h];
#pragma unroll
        for (int i = 0; i < 6; ++i) s += f[i] * w[i];
        op_ebf[idx] = f2bf(s);
        return;
    }
    idx -= NUM_OPS * HDIM;
    if (idx < NUM_MACH * HDIM) {
        int r = idx >> 7, h = idx & 127;
        const float* f = Fm + (size_t)r * 2;
        const float* w = Wm + (size_t)h * 2;
        float s = bm[h] + f[0] * w[0] + f[1] * w[1];
        mach_emb[idx] = s;
        mach_ebf[idx] = f2bf(s);
        return;
    }
    idx -= NUM_MACH * HDIM;
    if (idx < 2 * 128 * 256) {
        int l = idx >> 15, h = (idx >> 8) & 127, k = idx & 255;
        float v = (k < 128) ? Wp[(size_t)l * 16384 + h * 128 + k]
                            : Wc[(size_t)l * 16384 + h * 128 + (k - 128)];
        Wb[idx] = f2bf(v);
    }
}

// ---------------- front: coarse op-key histogram + machine histogram (shared comp_e read) ----
// BOTH histograms chunked over unified i-space [0, NT): column j counts items in i-chunk j.
__global__ __launch_bounds__(256) void k_front(const int* __restrict__ prec_e, int nprec,
                                               const int* __restrict__ comp_e, int E, int M,
                                               int* __restrict__ chist_bh,   // [784][256]
                                               int* __restrict__ mach_bh) {  // [512][256]
    __shared__ int hc[NCOARSE];
    __shared__ int hm[NUM_MACH];
    for (int i = threadIdx.x; i < NCOARSE; i += 256) hc[i] = 0;
    for (int i = threadIdx.x; i < NUM_MACH; i += 256) hm[i] = 0;
    __syncthreads();
    int NT = nprec + E;
    int ch = (NT + NBC - 1) / NBC;
    int i0 = blockIdx.x * ch, i1 = min(NT, i0 + ch);
    for (int i = i0 + threadIdx.x; i < i1; i += 256) {
        int key;
        if (i < nprec) key = prec_e[nprec + i];
        else {
            int e = i - nprec;
            key = P1 + comp_e[e];
            atomicAdd(&hm[comp_e[E + e] - M], 1);
        }
        atomicAdd(&hc[key >> 8], 1);
    }
    __syncthreads();
    for (int i = threadIdx.x; i < NCOARSE; i += 256)
        chist_bh[i * NBC + blockIdx.x] = hc[i];
    for (int i = threadIdx.x; i < NUM_MACH; i += 256)
        mach_bh[i * NBC + blockIdx.x] = hm[i];
}

// ---------------- coarse pass B: place packed (val<<8 | key&255) via LDS cursors ----------------
__global__ __launch_bounds__(256) void k_cfill(const int* __restrict__ prec_e, int nprec,
                                               const int* __restrict__ comp_e, int E, int M,
                                               const int* __restrict__ scan,
                                               int* __restrict__ pairs) {
    __shared__ int cur[NCOARSE];
    for (int i = threadIdx.x; i < NCOARSE; i += 256) cur[i] = scan[i * NBC + blockIdx.x];
    __syncthreads();
    int NT = nprec + E;
    int ch = (NT + NBC - 1) / NBC;
    int i0 = blockIdx.x * ch, i1 = min(NT, i0 + ch);
    for (int i = i0 + threadIdx.x; i < i1; i += 256) {
        int key, val;
        if (i < nprec) { key = prec_e[nprec + i]; val = prec_e[i]; }
        else { int e = i - nprec; key = P1 + comp_e[e]; val = comp_e[E + e] - M; }
        int pos = atomicAdd(&cur[key >> 8], 1);
        pairs[pos] = (val << 8) | (key & 255);
    }
}

// ---------------- scan phase 1: per-block sums over unified [chist|mach_bh] ----------------
__global__ __launch_bounds__(256) void k_blocksum(const int* __restrict__ arr, int* __restrict__ partial) {
    __shared__ int sh[256];
    int b = blockIdx.x, t = threadIdx.x;
    int4 v = *(const int4*)(arr + b * 1024 + t * 4);
    sh[t] = v.x + v.y + v.z + v.w;
    __syncthreads();
    for (int o = 128; o; o >>= 1) { if (t < o) sh[t] += sh[t + o]; __syncthreads(); }
    if (!t) partial[b] = sh[0];
}

// ---------------- scan phase 2: two independent segments (op: 196, machine: 128) --------------
__global__ __launch_bounds__(256) void k_scanpart(const int* __restrict__ partial,
                                                  int* __restrict__ block_off) {
    __shared__ int sh[256];
    int t = threadIdx.x;
    int seg0 = blockIdx.x ? NBLK : 0;
    int n    = blockIdx.x ? NBLK_M : NBLK;
    int v = (t < n) ? partial[seg0 + t] : 0;
    sh[t] = v; __syncthreads();
    for (int o = 1; o < 256; o <<= 1) {
        int x = (t >= o) ? sh[t - o] : 0; __syncthreads();
        sh[t] += x; __syncthreads();
    }
    if (t < n) block_off[seg0 + t] = sh[t] - v;
}

// ---------------- scan phase 3: write exclusive offsets (unified) ----------------
__global__ __launch_bounds__(256) void k_scanwrite(const int* __restrict__ arr,
                                                   const int* __restrict__ block_off,
                                                   int* __restrict__ rs) {
    __shared__ int sh[256];
    int b = blockIdx.x, t = threadIdx.x;
    int base_i = b * 1024 + t * 4;
    int4 v = *(const int4*)(arr + base_i);
    int tsum = v.x + v.y + v.z + v.w;
    sh[t] = tsum; __syncthreads();
    for (int o = 1; o < 256; o <<= 1) {
        int x = (t >= o) ? sh[t - o] : 0; __syncthreads();
        sh[t] += x; __syncthreads();
    }
    int off = block_off[b] + sh[t] - tsum;
    int4 r; r.x = off; r.y = off + v.x; r.z = off + v.x + v.y; r.w = off + v.x + v.y + v.z;
    *(int4*)(rs + base_i) = r;
}

// ---------------- fine counting sort (op keys) + machine placement + mach_rs, one launch -----
// Machine branch processes the e-range of NT-chunk blk, matching k_front's columns.
__global__ __launch_bounds__(256) void k_finefill(const int* __restrict__ scans, int NT,
                                                  const int* __restrict__ pairs,
                                                  int* __restrict__ rs,
                                                  int* __restrict__ bucket_all,
                                                  const int* __restrict__ comp_e, int E, int M,
                                                  int* __restrict__ bucket_mach,
                                                  int* __restrict__ mach_rs) {
    int t = threadIdx.x;
    if (blockIdx.x < NCOARSE) {
        __shared__ int hh[256];
        __shared__ int ex[256];
        __shared__ int cu[256];
        int b = blockIdx.x;
        int s = scans[b * NBC];
        int e = (b == NCOARSE - 1) ? NT : scans[(b + 1) * NBC];
        hh[t] = 0;
        __syncthreads();
        for (int i = s + t; i < e; i += 256) atomicAdd(&hh[pairs[i] & 255], 1);
        __syncthreads();
        int v = hh[t];
        ex[t] = v; __syncthreads();
        for (int o = 1; o < 256; o <<= 1) {
            int x = (t >= o) ? ex[t - o] : 0; __syncthreads();
            ex[t] += x; __syncthreads();
        }
        int start = s + ex[t] - v;
        rs[b * 256 + t] = start;
        cu[t] = start;
        __syncthreads();
        for (int i = s + t; i < e; i += 256) {
            int p = pairs[i];
            int pos = atomicAdd(&cu[p & 255], 1);
            bucket_all[pos] = ((unsigned)p) >> 8;
        }
    } else {
        __shared__ int cur[NUM_MACH];
        int blk = blockIdx.x - NCOARSE;
        const int* moff = scans + NHIST;
        for (int i = t; i < NUM_MACH; i += 256) cur[i] = moff[i * NBM + blk];
        if (blk == 0) {
            for (int m = t; m < NUM_MACH; m += 256) mach_rs[m] = moff[m * NBM];
            if (t == 0) mach_rs[NUM_MACH] = E;
        }
        __syncthreads();
        int nprec = NT - E;
        int chNT = (NT + NBC - 1) / NBC;            // SAME chunking as k_front
        int e0 = blk * chNT - nprec;       if (e0 < 0) e0 = 0;
        int e1 = (blk + 1) * chNT - nprec; if (e1 > E) e1 = E;
        for (int e = e0 + t; e < e1; e += 256) {
            int m = comp_e[E + e] - M;
            int op = comp_e[e];
            int pos = atomicAdd(&cur[m], 1);
            bucket_mach[pos] = op;
        }
    }
}

// ---------------- merged per-layer aggregation: op-side gather->Ab | machine-side gather ------
// blocks [0, nb_agg): op aggregation, DUAL-STREAM: prec (op_ebf) and m2o (mach_ebf) gathers
//   advance in lock-step, 8 edges/stream/iter -> 4 independent 16B loads per lane in flight.
// blocks [nb_agg, ...): machine gather, 16-edge staged batches (4 unmasked loads in flight).
__global__ __launch_bounds__(256) void k_aggmg(
    const unsigned short* __restrict__ op_ebf, const unsigned short* __restrict__ mach_ebf,
    const int* __restrict__ rs, const int* __restrict__ bucket_all,
    unsigned short* __restrict__ Ab, int* __restrict__ flags, int M,
    const int* __restrict__ mach_rs, const int* __restrict__ bucket_mach,
    float* __restrict__ mach_sum, int nb_agg) {
    int wave = threadIdx.x >> 6, lane = threadIdx.x & 63;
    int g = lane >> 4;               // edge sub-group 0..3
    int d = (lane & 15) * 8;         // dim base: 8 bf16 per lane

    if ((int)blockIdx.x < nb_agg) {
        // ---- op aggregation: dual-stream interleaved gather ----
        int r = blockIdx.x * 4 + wave;
        if (r >= M) return;
        int sA = rs[r],      eA = rs[r + 1];
        int sB = rs[P1 + r], eB = rs[P1 + r + 1];

        float a[8], b[8];
#pragma unroll
        for (int k = 0; k < 8; ++k) { a[k] = 0.f; b[k] = 0.f; }

        int baseA = sA, baseB = sB;
        while (baseA < eA || baseB < eB) {
            int cA = (baseA < eA) ? min(64, eA - baseA) : 0;
            int cB = (baseB < eB) ? min(64, eB - baseB) : 0;
            int idxA = (lane < cA) ? bucket_all[baseA + lane] : 0;
            int idxB = (lane < cB) ? bucket_all[baseB + lane] : 0;
            int jm = max(cA, cB);
            for (int j = 0; j < jm; j += 8) {
                int j0 = j + g, j1 = j + 4 + g;
                int rA0 = __shfl(idxA, j0);
                int rA1 = __shfl(idxA, j1);
                int rB0 = __shfl(idxB, j0);
                int rB1 = __shfl(idxB, j1);
                short8 vA0 = *(const short8*)(op_ebf   + (size_t)rA0 * HDIM + d);
                short8 vA1 = *(const short8*)(op_ebf   + (size_t)rA1 * HDIM + d);
                short8 vB0 = *(const short8*)(mach_ebf + (size_t)rB0 * HDIM + d);
                short8 vB1 = *(const short8*)(mach_ebf + (size_t)rB1 * HDIM + d);
                if (j0 < cA) {
#pragma unroll
                    for (int k = 0; k < 8; ++k) a[k] += bf2f((unsigned short)vA0[k]);
                }
                if (j1 < cA) {
#pragma unroll
                    for (int k = 0; k < 8; ++k) a[k] += bf2f((unsigned short)vA1[k]);
                }
                if (j0 < cB) {
#pragma unroll
                    for (int k = 0; k < 8; ++k) b[k] += bf2f((unsigned short)vB0[k]);
                }
                if (j1 < cB) {
#pragma unroll
                    for (int k = 0; k < 8; ++k) b[k] += bf2f((unsigned short)vB1[k]);
                }
            }
            baseA += 64; baseB += 64;
        }
#pragma unroll
        for (int k = 0; k < 8; ++k) {
            a[k] += __shfl_xor(a[k], 16);
            a[k] += __shfl_xor(a[k], 32);
            b[k] += __shfl_xor(b[k], 16);
            b[k] += __shfl_xor(b[k], 32);
        }
        float pinv = 1.f / fmaxf((float)(eA - sA), 1.f);
        float cinv = 1.f / fmaxf((float)(eB - sB), 1.f);

        if (lane < 16) {
            ushort8 pa, pb;
#pragma unroll
            for (int k = 0; k < 8; ++k) { pa[k] = f2bf(a[k] * pinv); pb[k] = f2bf(b[k] * cinv); }
            *(ushort8*)(Ab + (size_t)r * 256 + d)       = pa;
            *(ushort8*)(Ab + (size_t)r * 256 + 128 + d) = pb;
        }
        if (lane == 0) flags[r] = (eA > sA ? 1 : 0) | (eB > sB ? 2 : 0);
        return;
    }

    // ---- machine gather: 16-edge staged batches, 16 groups/machine, stride 1024 ----
    int b2 = blockIdx.x - nb_agg;
    int m  = b2 & 511;
    int yq = b2 >> 9;                 // 0..3
    int s0 = mach_rs[m], e0 = mach_rs[m + 1];
    float a[8];
#pragma unroll
    for (int k = 0; k < 8; ++k) a[k] = 0.f;

    for (int base = s0 + (yq * 4 + wave) * 64; base < e0; base += 1024) {
        int cnt = min(64, e0 - base);
        int idx = (lane < cnt) ? bucket_mach[base + lane] : 0;
        int j = 0;
        for (; j + 16 <= cnt; j += 16) {
            int r0 = __shfl(idx, j + g);
            int r1 = __shfl(idx, j + 4 + g);
            int r2 = __shfl(idx, j + 8 + g);
            int r3 = __shfl(idx, j + 12 + g);
            short8 v0 = *(const short8*)(op_ebf + (size_t)r0 * HDIM + d);
            short8 v1 = *(const short8*)(op_ebf + (size_t)r1 * HDIM + d);
            short8 v2 = *(const short8*)(op_ebf + (size_t)r2 * HDIM + d);
            short8 v3 = *(const short8*)(op_ebf + (size_t)r3 * HDIM + d);
#pragma unroll
            for (int k = 0; k < 8; ++k) a[k] += bf2f((unsigned short)v0[k]);
#pragma unroll
            for (int k = 0; k < 8; ++k) a[k] += bf2f((unsigned short)v1[k]);
#pragma unroll
            for (int k = 0; k < 8; ++k) a[k] += bf2f((unsigned short)v2[k]);
#pragma unroll
            for (int k = 0; k < 8; ++k) a[k] += bf2f((unsigned short)v3[k]);
        }
        for (; j < cnt; j += 4) {
            int jj = j + g;
            int rowi = __shfl(idx, jj);
            short8 v = *(const short8*)(op_ebf + (size_t)rowi * HDIM + d);
            if (jj < cnt) {
#pragma unroll
                for (int k = 0; k < 8; ++k) a[k] += bf2f((unsigned short)v[k]);
            }
        }
    }
#pragma unroll
    for (int k = 0; k < 8; ++k) {
        a[k] += __shfl_xor(a[k], 16);
        a[k] += __shfl_xor(a[k], 32);
    }
    if (lane < 16) {
#pragma unroll
        for (int k = 0; k < 8; ++k)
            atomicAdd(&mach_sum[m * HDIM + d + k], a[k]);
    }
}

// ---------------- MFMA GEMM + bf16 residual + bias-flags + LayerNorm -------------------------
// out[r] = LN(bf2f(embb[r]) + A[r,0:256]@Wb^T + fp*bp + fc*bc)
// In-place embb==dstb is safe: row r is read and written only by its own 16 lanes, read-first.
__global__ __launch_bounds__(256) void k_gemm_mfma(
    const unsigned short* __restrict__ Ab, const unsigned short* __restrict__ embb,
    const unsigned short* __restrict__ Wb,
    const float* __restrict__ bp, const float* __restrict__ bc,
    const int* __restrict__ flags,
    const float* __restrict__ g, const float* __restrict__ bt,
    float* __restrict__ dstf, unsigned short* __restrict__ dstb, int M) {
    int wave = threadIdx.x >> 6, lane = threadIdx.x & 63;
    int m0 = blockIdx.x * 64 + wave * 16;
    if (m0 >= M) return;
    int quad = lane >> 4, col = lane & 15;

    floatx4 acc[8];
#pragma unroll
    for (int t = 0; t < 8; ++t) acc[t] = (floatx4){0.f, 0.f, 0.f, 0.f};

    const short* Arow  = (const short*)(Ab + (size_t)(m0 + col) * 256);
    const short* Wbase = (const short*)Wb;

#pragma unroll
    for (int ks = 0; ks < 8; ++ks) {
        short8 a = *(const short8*)(Arow + ks * 32 + quad * 8);
#pragma unroll
        for (int t = 0; t < 8; ++t) {
            short8 b = *(const short8*)(Wbase + (size_t)(t * 16 + col) * 256 + ks * 32 + quad * 8);
            acc[t] = __builtin_amdgcn_mfma_f32_16x16x32_bf16(a, b, acc[t], 0, 0, 0);
        }
    }

    float bpv[8], bcv[8], gv[8], btv[8];
#pragma unroll
    for (int t = 0; t < 8; ++t) {
        int c = t * 16 + col;
        bpv[t] = bp[c]; bcv[t] = bc[c]; gv[t] = g[c]; btv[t] = bt[c];
    }
#pragma unroll
    for (int reg = 0; reg < 4; ++reg) {
        int r = m0 + quad * 4 + reg;
        int fl = flags[r];
        float fp = (fl & 1) ? 1.f : 0.f, fc = (fl & 2) ? 1.f : 0.f;
        float x[8]; float s = 0.f, q = 0.f;
#pragma unroll
        for (int t = 0; t < 8; ++t) {
            float v = acc[t][reg] + bf2f(embb[(size_t)r * HDIM + t * 16 + col]) + fp * bpv[t] + fc * bcv[t];
            x[t] = v; s += v; q += v * v;
        }
#pragma unroll
        for (int msk = 1; msk < 16; msk <<= 1) { s += __shfl_xor(s, msk); q += __shfl_xor(q, msk); }
        float mu = s * (1.f / 128.f);
        float rstd = rsqrtf(fmaxf(q * (1.f / 128.f) - mu * mu, 0.f) + 1e-5f);
#pragma unroll
        for (int t = 0; t < 8; ++t) {
            float y = (x[t] - mu) * rstd * gv[t] + btv[t];
            if (dstf) dstf[(size_t)r * HDIM + t * 16 + col] = y;
            if (dstb) dstb[(size_t)r * HDIM + t * 16 + col] = f2bf(y);
        }
    }
}

// ---------------- machine update: mean -> @Wc^T + bc -> +emb -> LN (+ optional bf16 mirror) --
__global__ __launch_bounds__(128) void k_mach_update(
    const float* __restrict__ mach_emb, const float* __restrict__ mach_sum,
    const int* __restrict__ mach_rs,
    const float* __restrict__ Wc, const float* __restrict__ bc,
    const float* __restrict__ g, const float* __restrict__ bt,
    float* __restrict__ dst, unsigned short* __restrict__ dstb) {
    __shared__ float row[HDIM];
    __shared__ float red[4];
    int m = blockIdx.x, t = threadIdx.x;
    int cnt = mach_rs[m + 1] - mach_rs[m];
    float sc = (cnt > 0) ? 1.f / (float)cnt : 0.f;
    row[t] = mach_sum[m * HDIM + t] * sc;
    __syncthreads();
    float dot = bc[t];
    const float* w = Wc + (size_t)t * HDIM;
#pragma unroll 8
    for (int k = 0; k < HDIM; ++k) dot += row[k] * w[k];
    float x = mach_emb[m * HDIM + t] + ((cnt > 0) ? dot : 0.f);
    float s = x, q = x * x;
#pragma unroll
    for (int o = 32; o; o >>= 1) { s += __shfl_xor(s, o); q += __shfl_xor(q, o); }
    int wv = t >> 6;
    if ((t & 63) == 0) { red[wv * 2] = s; red[wv * 2 + 1] = q; }
    __syncthreads();
    s = red[0] + red[2]; q = red[1] + red[3];
    float mu = s * (1.f / 128.f);
    float rstd = rsqrtf(fmaxf(q * (1.f / 128.f) - mu * mu, 0.f) + 1e-5f);
    float y = (x - mu) * rstd * g[t] + bt[t];
    dst[m * HDIM + t] = y;
    if (dstb) dstb[m * HDIM + t] = f2bf(y);
}

extern "C" void kernel_launch(void* const* d_in, const int* in_sizes, int n_in,
                              void* d_out, int out_size, void* d_ws, size_t ws_size,
                              hipStream_t stream) {
    const float* op_feat    = (const float*)d_in[0];
    const float* m_feat     = (const float*)d_in[1];
    const int*   prec_e     = (const int*)d_in[2];
    const int*   comp_e     = (const int*)d_in[3];
    const float* op_emb_W   = (const float*)d_in[4];
    const float* op_emb_b   = (const float*)d_in[5];
    const float* mach_emb_W = (const float*)d_in[6];
    const float* mach_emb_b = (const float*)d_in[7];
    const float* prec_W     = (const float*)d_in[8];
    const float* prec_b     = (const float*)d_in[9];
    const float* compat_W   = (const float*)d_in[10];
    const float* compat_b   = (const float*)d_in[11];
    const float* op_ln_g    = (const float*)d_in[12];
    const float* op_ln_b    = (const float*)d_in[13];
    const float* mach_ln_g  = (const float*)d_in[14];
    const float* mach_ln_b  = (const float*)d_in[15];
    float* out = (float*)d_out;

    const int M = NUM_OPS, NM = NUM_MACH;
    const int nprec = in_sizes[2] / 2;
    const int ncomp = in_sizes[3] / 2;
    const int E = ncomp / 2;   // bidirectional pairs: first half o2m, second half m2o (mirror)
    const int NT = nprec + E;

    float* ws = (float*)d_ws;
    size_t o = 0;
    unsigned short* op_ebf = (unsigned short*)(ws + o); o += (size_t)M * 64;   // 25.6 MB bf16 state
    unsigned short* Ab = (unsigned short*)(ws + o); o += (size_t)M * 128;  // 51 MB bf16 [M][256]
    unsigned short* Wb = (unsigned short*)(ws + o); o += 32768;            // 2 layers x [128][256] bf16
    float* mach_emb = ws + o; o += (size_t)NM * HDIM;
    unsigned short* mach_ebf = (unsigned short*)(ws + o); o += (size_t)NM * 64;
    float* mach_sum = ws + o; o += (size_t)NM * HDIM;
    int* ip = (int*)(ws + o);
    size_t io = 0;
    int* hists     = ip + io; io += NHIST + MHWORDS;  // [chist 784x256 | mach_bh 512x256]
    int* scans     = ip + io; io += NHIST + MHWORDS;  // [cscan | moff] (exclusive offsets)
    int* rs        = ip + io; io += NHIST;            // fine row starts (exclusive)
    int* mach_rs   = ip + io; io += NM + 8;
    int* partialT  = ip + io; io += 512;              // unified block sums (324 used)
    int* block_off = ip + io; io += 512;
    int* flags     = ip + io; io += M;
    int* pairs     = ip + io; io += (size_t)NT;       // coarse-partitioned packed edges
    int* bucket_all  = ip + io; io += (size_t)NT;
    int* bucket_mach = ip + io; io += (size_t)E;

    int* mach_bh = hists + NHIST;

    // ---- CSR build: two-level counting sort, 6 launches ----
    k_front<<<NBC, 256, 0, stream>>>(prec_e, nprec, comp_e, E, M, hists, mach_bh);
    k_blocksum<<<NBLK_T, 256, 0, stream>>>(hists, partialT);
    k_scanpart<<<2, 256, 0, stream>>>(partialT, block_off);
    k_scanwrite<<<NBLK_T, 256, 0, stream>>>(hists, block_off, scans);
    k_cfill<<<NBC, 256, 0, stream>>>(prec_e, nprec, comp_e, E, M, scans, pairs);
    k_finefill<<<NCOARSE + NBM, 256, 0, stream>>>(scans, NT, pairs, rs, bucket_all,
                                                  comp_e, E, M, bucket_mach, mach_rs);

    // ---- embeddings + weight conversion, one launch ----
    int prep_total = (M + NM) * HDIM + 2 * 128 * 256;
    k_prep<<<(prep_total + 255) / 256, 256, 0, stream>>>(
        op_feat, m_feat, op_emb_W, op_emb_b, mach_emb_W, mach_emb_b,
        prec_W, compat_W, op_ebf, mach_emb, mach_ebf, Wb);

    const int nb_agg = (M + 3) / 4;
    for (int l = 0; l < 2; ++l) {
        int last = (l == 1);
        const float* bpl = prec_b   + (size_t)l * HDIM;
        const float* Wc  = compat_W + (size_t)l * HDIM * HDIM;
        const float* bcl = compat_b + (size_t)l * HDIM;

        hipMemsetAsync(mach_sum, 0, (size_t)NM * HDIM * sizeof(float), stream);

        // merged: op-side aggregation (writes Ab/flags) + machine-side gather (atomics mach_sum)
        // reads op_ebf + mach_ebf (both old); completes before updates overwrite them
        k_aggmg<<<nb_agg + NM * 4, 256, 0, stream>>>(
            op_ebf, mach_ebf, rs, bucket_all, Ab, flags, M,
            mach_rs, bucket_mach, mach_sum, nb_agg);

        // op update: reads Ab + bf16 residual, writes bf16 state in-place (or f32 out at last)
        k_gemm_mfma<<<(M + 63) / 64, 256, 0, stream>>>(
            Ab, op_ebf, Wb + (size_t)l * 128 * 256, bpl, bcl, flags,
            op_ln_g + (size_t)l * HDIM, op_ln_b + (size_t)l * HDIM,
            last ? out : nullptr, last ? nullptr : op_ebf, M);

        // machine update (overwrites mach_emb/mach_ebf after k_aggmg read them)
        k_mach_update<<<NM, 128, 0, stream>>>(
            mach_emb, mach_sum, mach_rs, Wc, bcl,
            mach_ln_g + (size_t)l * HDIM, mach_ln_b + (size_t)l * HDIM,
            last ? (out + (size_t)M * HDIM) : mach_emb, last ? nullptr : mach_ebf);
    }
}